// Round 2
// baseline (1900.026 us; speedup 1.0000x reference)
//
#include <hip/hip_runtime.h>
#include <hip/hip_bf16.h>

// I/O dtype: float32 (per reference setup_inputs / outputs). Internal f32.
// Tolerance (9.9e-2) budgets for bf16 internal math -> future MFMA rounds.
//
// Geometry: levels (100,100),(50,50),(25,25),(13,13),(7,7)
//   offsets 0, 10000, 12500, 13125, 13294 ; L = 13343 ; N = 2 ; NLq = 26686

#define LTOT 13343
#define NLQ  26686

// ---------------------------------------------------------------------------
// Generic tiled GEMM: out = epi(A @ W^T + bias)
// AMODE: 0 = f32 rowmajor with (HW,L,off) row mapping
//        1 = f32 NCHW (1x1 conv),  2 = f32 im2col 3x3 s2 p1 on 13x13x1024
// EPI:   0 = bias->f32, 1 = bias+sigmoid->f32, 2 = bias+relu->f32,
//        3 = atomicAdd f32 (no bias; k-split), 4 = bias->f32 NCHW
// ---------------------------------------------------------------------------
template<int AMODE, int EPI>
__global__ __launch_bounds__(256) void gemm_k(
    const float* __restrict__ A, const float* __restrict__ W,
    const float* __restrict__ bias, float* __restrict__ out,
    int M, int Nc, int K, int k_len,
    int A_HW, int A_L, int A_off,
    int O_HW, int O_L, int O_off)
{
  __shared__ float As[16][68];
  __shared__ float Ws[16][68];
  int tid = threadIdx.x;
  int bm = blockIdx.x * 64, bn = blockIdx.y * 64;
  int k0 = blockIdx.z * k_len;
  int tn = tid & 15, tm = tid >> 4;
  float acc[4][4] = {};

  for (int kt = k0; kt < k0 + k_len; kt += 16) {
    if (AMODE == 0) {
      int kk = tid & 15, mm = tid >> 4;
#pragma unroll
      for (int i = 0; i < 4; i++) {
        int m = bm + mm + i * 16;
        float v = 0.f;
        if (m < M) {
          int n = m / A_HW, p = m - n * A_HW;
          v = A[((size_t)(n * A_L + A_off + p)) * K + kt + kk];
        }
        As[kk][mm + i * 16] = v;
      }
    } else if (AMODE == 1) {
      int mm = tid & 63, kq = tid >> 6;
      int m = bm + mm;
      bool ok = m < M;
      int n = 0, p = 0;
      if (ok) { n = m / A_HW; p = m - n * A_HW; }
#pragma unroll
      for (int i = 0; i < 4; i++) {
        int kk = kq * 4 + i;
        float v = 0.f;
        if (ok) v = A[((size_t)n * K + kt + kk) * A_HW + p];
        As[kk][mm] = v;
      }
    } else {
      int mm = tid & 63, kq = tid >> 6;
      int m = bm + mm;
      bool ok = m < M;
      int n = 0, oh = 0, ow = 0;
      if (ok) { n = m / 49; int p = m - n * 49; oh = p / 7; ow = p - oh * 7; }
#pragma unroll
      for (int i = 0; i < 4; i++) {
        int kk = kq * 4 + i;
        float v = 0.f;
        if (ok) {
          int kg = kt + kk;
          int c = kg / 9, rs = kg - c * 9;
          int r = rs / 3, s = rs - r * 3;
          int ih = oh * 2 - 1 + r, iw = ow * 2 - 1 + s;
          if (ih >= 0 && ih < 13 && iw >= 0 && iw < 13)
            v = A[((size_t)(n * 1024 + c) * 13 + ih) * 13 + iw];
        }
        As[kk][mm] = v;
      }
    }
    {
      int kk = tid & 15, nn = tid >> 4;
#pragma unroll
      for (int i = 0; i < 4; i++) {
        int nc = bn + nn + i * 16;
        float v = 0.f;
        if (nc < Nc) v = W[(size_t)nc * K + kt + kk];
        Ws[kk][nn + i * 16] = v;
      }
    }
    __syncthreads();
#pragma unroll
    for (int kk = 0; kk < 16; kk++) {
      float4 a4 = *(const float4*)&As[kk][tm * 4];
      float4 b4 = *(const float4*)&Ws[kk][tn * 4];
      float av[4] = {a4.x, a4.y, a4.z, a4.w};
      float bv[4] = {b4.x, b4.y, b4.z, b4.w};
#pragma unroll
      for (int i = 0; i < 4; i++)
#pragma unroll
        for (int j = 0; j < 4; j++) acc[i][j] = fmaf(av[i], bv[j], acc[i][j]);
    }
    __syncthreads();
  }

#pragma unroll
  for (int i = 0; i < 4; i++) {
    int m = bm + tm * 4 + i;
    if (m >= M) continue;
    int n = m / O_HW, p = m - n * O_HW;
    size_t orow = (size_t)(n * O_L + O_off + p);
#pragma unroll
    for (int j = 0; j < 4; j++) {
      int c = bn + tn * 4 + j;
      if (c >= Nc) continue;
      float v = acc[i][j];
      if (EPI != 3) v += bias[c];
      if (EPI == 1) v = 1.f / (1.f + expf(-v));
      if (EPI == 2) v = fmaxf(v, 0.f);
      if (EPI == 4) {
        out[((size_t)n * Nc + c) * O_HW + p] = v;
      } else if (EPI == 3) {
        atomicAdd(out + orow * Nc + c, v);
      } else {
        out[orow * Nc + c] = v;
      }
    }
  }
}

// init level-4 rows of src with conv bias (conv3x3 accumulates atomically)
__global__ __launch_bounds__(256) void biasinit_k(float* __restrict__ src,
                                                  const float* __restrict__ bias)
{
  int blk = blockIdx.x;        // 0..97
  int n = blk / 49, p = blk - n * 49;
  src[((size_t)(n * LTOT + 13294 + p)) * 256 + threadIdx.x] = bias[threadIdx.x];
}

// x1 (N,256,50,50) -> src rows [10000,12500) (transpose)
__global__ __launch_bounds__(256) void copy_lvl1_in_k(const float* __restrict__ x,
                                                      float* __restrict__ src)
{
  __shared__ float tile[32][33];
  int p0 = blockIdx.x * 32, c0 = blockIdx.y * 32, n = blockIdx.z;
  int tx = threadIdx.x & 31, ty = threadIdx.x >> 5;
  for (int i = ty; i < 32; i += 8) {
    int c = c0 + i, p = p0 + tx;
    float v = 0.f;
    if (p < 2500) v = x[((size_t)n * 256 + c) * 2500 + p];
    tile[i][tx] = v;
  }
  __syncthreads();
  for (int i = ty; i < 32; i += 8) {
    int p = p0 + i, c = c0 + tx;
    if (p < 2500) src[((size_t)(n * LTOT + 10000 + p)) * 256 + c] = tile[tx][i];
  }
}

// h2 rows [10000,12500) -> out1 (N,256,50,50) (transpose)
__global__ __launch_bounds__(256) void copy_lvl1_out_k(const float* __restrict__ h2,
                                                       float* __restrict__ out)
{
  __shared__ float tile[32][33];
  int p0 = blockIdx.x * 32, c0 = blockIdx.y * 32, n = blockIdx.z;
  int tx = threadIdx.x & 31, ty = threadIdx.x >> 5;
  for (int i = ty; i < 32; i += 8) {
    int p = p0 + i, c = c0 + tx;
    float v = 0.f;
    if (p < 2500) v = h2[((size_t)(n * LTOT + 10000 + p)) * 256 + c];
    tile[tx][i] = v;  // tile[c_local][p_local]
  }
  __syncthreads();
  for (int i = ty; i < 32; i += 8) {
    int c = c0 + i, p = p0 + tx;
    if (p < 2500) out[((size_t)n * 256 + c) * 2500 + p] = tile[i][tx];
  }
}

// GroupNorm stats over conv levels {0,2,3,4}; 256 blocks = 4 lvl * 2 n * 32 grp
__global__ __launch_bounds__(256) void gn_stats_k(const float* __restrict__ src,
                                                  float* __restrict__ stats)
{
  const int offs[4] = {0, 12500, 13125, 13294};
  const int hws[4]  = {10000, 625, 169, 49};
  int b = blockIdx.x;
  int li = b >> 6, n = (b >> 5) & 1, g = b & 31;
  int off = offs[li], hw = hws[li];
  int cnt = hw * 8;
  float s = 0.f, s2 = 0.f;
  for (int i = threadIdx.x; i < cnt; i += 256) {
    int p = i >> 3, j = i & 7;
    float v = src[((size_t)(n * LTOT + off + p)) * 256 + g * 8 + j];
    s += v; s2 += v * v;
  }
  __shared__ float r1[4], r2[4];
  for (int o = 32; o; o >>= 1) { s += __shfl_down(s, o, 64); s2 += __shfl_down(s2, o, 64); }
  int t = threadIdx.x;
  if ((t & 63) == 0) { r1[t >> 6] = s; r2[t >> 6] = s2; }
  __syncthreads();
  if (t == 0) {
    float S = r1[0] + r1[1] + r1[2] + r1[3];
    float S2 = r2[0] + r2[1] + r2[2] + r2[3];
    float mean = S / (float)cnt;
    float var = S2 / (float)cnt - mean * mean;
    int si = (li * 2 + n) * 32 + g;
    stats[si * 2] = mean;
    stats[si * 2 + 1] = rsqrtf(var + 1e-5f);
  }
}

__global__ __launch_bounds__(256) void gn_apply_k(float* __restrict__ src,
    const float* __restrict__ stats, const float* __restrict__ g,
    const float* __restrict__ b, int off, int hw, int li)
{
  int blk = blockIdx.x;
  int n = blk / hw, p = blk - n * hw;
  int t = threadIdx.x;
  int si = (li * 2 + n) * 32 + (t >> 3);
  float mean = stats[si * 2], rstd = stats[si * 2 + 1];
  size_t a = ((size_t)(n * LTOT + off + p)) * 256 + t;
  float v = src[a];
  src[a] = (v - mean) * rstd * g[t] + b[t];
}

// softmax over 20 within each (n,q,h); aw row = 160 floats
__global__ __launch_bounds__(256) void softmax20_k(float* __restrict__ aw, int total)
{
  int i = blockIdx.x * 256 + threadIdx.x;
  if (i >= total) return;
  float* p = aw + (size_t)(i >> 3) * 160 + (i & 7) * 20;
  float m = p[0];
#pragma unroll
  for (int j = 1; j < 20; j++) m = fmaxf(m, p[j]);
  float e[20], s = 0.f;
#pragma unroll
  for (int j = 0; j < 20; j++) { e[j] = expf(p[j] - m); s += e[j]; }
  float inv = 1.f / s;
#pragma unroll
  for (int j = 0; j < 20; j++) p[j] = e[j] * inv;
}

__device__ __forceinline__ float corner_val(const float* __restrict__ vlvl,
                                            int ix, int iy, int W, float w)
{
  bool valid = (ix >= 0) && (ix < W) && (iy >= 0) && (iy < W);
  int cx = min(max(ix, 0), W - 1), cy = min(max(iy, 0), W - 1);
  float v = vlvl[(size_t)(cy * W + cx) * 256];
  return valid ? v * w : 0.f;
}

// deformable attention sampling; block = one (n,q), thread = (head h, dim d)
__global__ __launch_bounds__(256) void msdeform_k(const float* __restrict__ value,
    const float* __restrict__ offb, const float* __restrict__ awb,
    const float* __restrict__ refb, float* __restrict__ out)
{
  const int Wl[5]   = {100, 50, 25, 13, 7};
  const int lvlo[5] = {0, 10000, 12500, 13125, 13294};
  int q = blockIdx.x;                  // 0..NLQ-1 global row
  int n = q / LTOT;
  int t = threadIdx.x;
  int h = t >> 5, d = t & 31;
  __shared__ float s_off[320], s_aw[160], s_ref[10];
  {
    const float* orow = offb + (size_t)q * 320;
    const float* arow = awb + (size_t)q * 160;
    const float* rrow = refb + (size_t)q * 10;
    for (int i = t; i < 320; i += 256) s_off[i] = orow[i];
    if (t < 160) s_aw[t] = arow[t];
    if (t < 10)  s_ref[t] = rrow[t];
  }
  __syncthreads();
  float acc = 0.f;
  const float* vbase = value + (size_t)n * LTOT * 256 + h * 32 + d;
#pragma unroll
  for (int l = 0; l < 5; l++) {
    int W = Wl[l];
    float fW = (float)W;
    float rx = s_ref[l * 2], ry = s_ref[l * 2 + 1];
    const float* vlvl = vbase + (size_t)lvlo[l] * 256;
#pragma unroll
    for (int pp = 0; pp < 4; pp++) {
      int oi = ((h * 5 + l) * 4 + pp) * 2;
      float lx = rx + s_off[oi] / fW;       // norm = (wl, hl); square levels
      float ly = ry + s_off[oi + 1] / fW;
      float wgt = s_aw[h * 20 + l * 4 + pp];
      float x = lx * fW - 0.5f, y = ly * fW - 0.5f;
      float x0f = floorf(x), y0f = floorf(y);
      float wx = x - x0f, wy = y - y0f;
      int x0 = (int)x0f, y0 = (int)y0f;
      float s = corner_val(vlvl, x0,     y0,     W, (1.f - wx) * (1.f - wy))
              + corner_val(vlvl, x0 + 1, y0,     W, wx * (1.f - wy))
              + corner_val(vlvl, x0,     y0 + 1, W, (1.f - wx) * wy)
              + corner_val(vlvl, x0 + 1, y0 + 1, W, wx * wy);
      acc += wgt * s;
    }
  }
  out[(size_t)q * 256 + t] = acc;
}

// y = LayerNorm(a + y) * g + b, row-wise over 256
__global__ __launch_bounds__(256) void ln_resid_k(const float* __restrict__ a,
    float* __restrict__ y, const float* __restrict__ g,
    const float* __restrict__ b)
{
  __shared__ float red[4];
  int row = blockIdx.x, t = threadIdx.x;
  size_t idx = (size_t)row * 256 + t;
  float v = a[idx] + y[idx];
  float s = v;
  for (int o = 32; o; o >>= 1) s += __shfl_down(s, o, 64);
  if ((t & 63) == 0) red[t >> 6] = s;
  __syncthreads();
  float mean = (red[0] + red[1] + red[2] + red[3]) * (1.f / 256.f);
  __syncthreads();
  float d = v - mean;
  float s2 = d * d;
  for (int o = 32; o; o >>= 1) s2 += __shfl_down(s2, o, 64);
  if ((t & 63) == 0) red[t >> 6] = s2;
  __syncthreads();
  float var = (red[0] + red[1] + red[2] + red[3]) * (1.f / 256.f);
  float rstd = rsqrtf(var + 1e-5f);
  y[idx] = d * rstd * g[t] + b[t];
}

extern "C" void kernel_launch(void* const* d_in, const int* in_sizes, int n_in,
                              void* d_out, int out_size, void* d_ws, size_t ws_size,
                              hipStream_t stream)
{
  const float* x0    = (const float*)d_in[0];
  const float* x1    = (const float*)d_in[1];
  const float* x2    = (const float*)d_in[2];
  const float* x3    = (const float*)d_in[3];
  const float* W_ref = (const float*)d_in[4];
  const float* b_ref = (const float*)d_in[5];
  const float* W_off = (const float*)d_in[6];
  const float* b_off = (const float*)d_in[7];
  const float* W_aw  = (const float*)d_in[8];
  const float* b_aw  = (const float*)d_in[9];
  const float* W_val = (const float*)d_in[10];
  const float* b_val = (const float*)d_in[11];
  const float* W_outp= (const float*)d_in[12];
  const float* b_outp= (const float*)d_in[13];
  const float* gn_g  = (const float*)d_in[14];
  const float* gn_b  = (const float*)d_in[15];
  const float* Wc1   = (const float*)d_in[16];
  const float* bc1   = (const float*)d_in[17];
  const float* Wc2   = (const float*)d_in[18];
  const float* bc2   = (const float*)d_in[19];
  const float* Wc3   = (const float*)d_in[20];
  const float* bc3   = (const float*)d_in[21];
  const float* Wc4   = (const float*)d_in[22];
  const float* bc4   = (const float*)d_in[23];
  const float* Wc11  = (const float*)d_in[24];
  const float* bc11  = (const float*)d_in[25];
  const float* Wc22  = (const float*)d_in[26];
  const float* bc22  = (const float*)d_in[27];
  const float* Wc33  = (const float*)d_in[28];
  const float* bc33  = (const float*)d_in[29];
  const float* ln1_g = (const float*)d_in[30];
  const float* ln1_b = (const float*)d_in[31];
  const float* W1    = (const float*)d_in[32];
  const float* b1f   = (const float*)d_in[33];
  const float* W2    = (const float*)d_in[34];
  const float* b2f_  = (const float*)d_in[35];
  const float* ln2_g = (const float*)d_in[36];
  const float* ln2_b = (const float*)d_in[37];

  // workspace layout (f32 elements)
  const size_t S = (size_t)NLQ * 256;          // 6,831,616
  float* ws   = (float*)d_ws;
  float* src  = ws;
  float* valb = ws + S;
  float* h1   = ws + 2 * S;
  float* R    = ws + 3 * S;                    // phase1 bufs, later FFN mid
  float* offb = R;
  float* awb  = offb + (size_t)NLQ * 320;
  float* refb = awb + (size_t)NLQ * 160;
  float* samp = refb + (size_t)NLQ * 10;
  float* mid  = R;                             // NLQ*1024
  float* stats = R + (size_t)NLQ * 1024;       // 512 floats
  const size_t needed = (3 * S + (size_t)NLQ * 1024 + 512) * 4;
  if (ws_size < needed) return;  // fail loudly rather than corrupt

  const int L = LTOT;
  dim3 B(256);

  // ---- input convs + GN into src ----
  gemm_k<1,0><<<dim3(313,4,1),B,0,stream>>>(x0, Wc1, bc1, src, 20000,256,128,128, 10000,0,0, 10000,L,0);
  gemm_k<1,0><<<dim3(20,4,1), B,0,stream>>>(x2, Wc2, bc2, src, 1250,256,512,512, 625,0,0, 625,L,12500);
  gemm_k<1,0><<<dim3(6,4,1),  B,0,stream>>>(x3, Wc3, bc3, src, 338,256,1024,1024, 169,0,0, 169,L,13125);
  biasinit_k<<<98,B,0,stream>>>(src, bc4);
  gemm_k<2,3><<<dim3(2,4,8),  B,0,stream>>>(x3, Wc4, bc4, src, 98,256,9216,1152, 0,0,0, 49,L,13294);
  copy_lvl1_in_k<<<dim3(79,8,2),B,0,stream>>>(x1, src);
  gn_stats_k<<<256,B,0,stream>>>(src, stats);
  gn_apply_k<<<20000,B,0,stream>>>(src, stats, gn_g, gn_b, 0,     10000, 0);
  gn_apply_k<<<1250, B,0,stream>>>(src, stats, gn_g, gn_b, 12500, 625,   1);
  gn_apply_k<<<338,  B,0,stream>>>(src, stats, gn_g, gn_b, 13125, 169,   2);
  gn_apply_k<<<98,   B,0,stream>>>(src, stats, gn_g, gn_b, 13294, 49,    3);

  // ---- projections ----
  gemm_k<0,0><<<dim3(417,4),B,0,stream>>>(src, W_val, b_val, valb, NLQ,256,256,256, NLQ,0,0, NLQ,0,0);
  gemm_k<0,0><<<dim3(417,5),B,0,stream>>>(src, W_off, b_off, offb, NLQ,320,256,256, NLQ,0,0, NLQ,0,0);
  gemm_k<0,0><<<dim3(417,3),B,0,stream>>>(src, W_aw,  b_aw,  awb,  NLQ,160,256,256, NLQ,0,0, NLQ,0,0);
  gemm_k<0,1><<<dim3(417,1),B,0,stream>>>(src, W_ref, b_ref, refb, NLQ,10, 256,256, NLQ,0,0, NLQ,0,0);
  softmax20_k<<<834,B,0,stream>>>(awb, NLQ * 8);
  msdeform_k<<<NLQ,B,0,stream>>>(valb, offb, awb, refb, samp);

  // ---- out-proj + LN1 ----
  gemm_k<0,0><<<dim3(417,4),B,0,stream>>>(samp, W_outp, b_outp, h1, NLQ,256,256,256, NLQ,0,0, NLQ,0,0);
  ln_resid_k<<<NLQ,B,0,stream>>>(src, h1, ln1_g, ln1_b);

  // ---- FFN + LN2 (h2 reuses valb) ----
  gemm_k<0,2><<<dim3(417,16),B,0,stream>>>(h1,  W1, b1f,  mid,  NLQ,1024,256,256, NLQ,0,0, NLQ,0,0);
  gemm_k<0,0><<<dim3(417,4), B,0,stream>>>(mid, W2, b2f_, valb, NLQ,256,1024,1024, NLQ,0,0, NLQ,0,0);
  ln_resid_k<<<NLQ,B,0,stream>>>(h1, valb, ln2_g, ln2_b);

  // ---- output convs / copies ----
  float* out = (float*)d_out;
  gemm_k<0,4><<<dim3(313,2),B,0,stream>>>(valb, Wc11, bc11, out,           20000,128,256,256, 10000,L,0,   10000,0,0);
  copy_lvl1_out_k<<<dim3(79,8,2),B,0,stream>>>(valb, out + 2560000);
  gemm_k<0,4><<<dim3(20,8), B,0,stream>>>(valb, Wc22, bc22, out + 3840000, 1250,512,256,256,  625,L,12500, 625,0,0);
  gemm_k<0,4><<<dim3(6,16), B,0,stream>>>(valb, Wc33, bc33, out + 4480000, 338,1024,256,256,  169,L,13125, 169,0,0);
}

// Round 3
// 1063.748 us; speedup vs baseline: 1.7862x; 1.7862x over previous
//
#include <hip/hip_runtime.h>
#include <hip/hip_bf16.h>

// I/O f32. Internal: bf16 MFMA GEMMs (threshold 9.9e-2 budgets bf16), f32 else.
// Levels (100,100),(50,50),(25,25),(13,13),(7,7); offsets 0,10000,12500,13125,13294
#define LTOT 13343
#define NLQ  26686

typedef __attribute__((ext_vector_type(8))) short bf16x8;
typedef __attribute__((ext_vector_type(4))) float f32x4;

__device__ __forceinline__ short f2bs(float x) {
  __hip_bfloat16 h = __float2bfloat16(x);
  return __builtin_bit_cast(short, h);
}
__device__ __forceinline__ bf16x8 cvt8(float4 a, float4 b) {
  bf16x8 v;
  v[0]=f2bs(a.x); v[1]=f2bs(a.y); v[2]=f2bs(a.z); v[3]=f2bs(a.w);
  v[4]=f2bs(b.x); v[5]=f2bs(b.y); v[6]=f2bs(b.z); v[7]=f2bs(b.w);
  return v;
}

// ---------------------------------------------------------------------------
// MFMA GEMM: out = epi(A(bf16) @ W(f32->bf16)^T + bias)
// 128x128 tile, K-step 32, 4 waves, 16x16x32 bf16 MFMA, 4x4 frags/wave.
// LDS fragment-linear: subtile s (16 rows x 32 k) = 64 lanes x 16B contiguous.
// AMODE: 0 = bf16 rowmajor [row][K] w/ (A_HW,A_L,A_off) row map
//        1 = im2col 3x3 s2 p1 from xt3 [n][169][1024], K' = rs*1024+c
// EPI: 0 bias->f32 rowmap | 1 bias+sigmoid->f32 | 2 bias+relu->bf16 rowmap
//      3 atomicAdd f32 (k-split) | 4 bias->f32 NCHW
// WMODE: 0 = W[Nc][K] k-contig | 1 = conv4 W[nc][c*9+rs] remap
// ---------------------------------------------------------------------------
template<int AMODE, int EPI, int WMODE>
__global__ __launch_bounds__(256) void mgemm_k(
    const __hip_bfloat16* __restrict__ A, const float* __restrict__ W,
    const float* __restrict__ bias, void* __restrict__ outv,
    int M, int Nc, int K, int k_len,
    int A_HW, int A_L, int A_off,
    int O_HW, int O_L, int O_off)
{
  __shared__ __hip_bfloat16 ldsA[4096];   // 8 KB
  __shared__ __hip_bfloat16 ldsB[4096];   // 8 KB
  const int t = threadIdx.x;
  const int bm = blockIdx.x * 128, bn = blockIdx.y * 128;
  const int k0 = blockIdx.z * k_len;

  // staging geometry: write w = t and w = t+256; s = w>>6, lane-in-subtile sl
  const int sl = t & 63;
  const int mloc = sl & 15;
  const int kbase = (sl >> 4) * 8;
  const int s0 = t >> 6;

  const int r0 = bm + s0 * 16 + mloc, r1 = r0 + 64;
  const int nc0 = bn + s0 * 16 + mloc, nc1 = nc0 + 64;

  const __hip_bfloat16 *ap0 = A, *ap1 = A;
  bool av0 = false, av1 = false;
  int g0n=0, g0h=0, g0w=0, g1n=0, g1h=0, g1w=0;
  if (AMODE == 0) {
    if (r0 < M) { int nn = r0 / A_HW, p = r0 - nn * A_HW;
      ap0 = A + (size_t)(nn * A_L + A_off + p) * K + kbase; av0 = true; }
    if (r1 < M) { int nn = r1 / A_HW, p = r1 - nn * A_HW;
      ap1 = A + (size_t)(nn * A_L + A_off + p) * K + kbase; av1 = true; }
  } else {
    if (r0 < M) { g0n = r0 / 49; int p = r0 - g0n * 49; g0h = p / 7; g0w = p - g0h * 7; av0 = true; }
    if (r1 < M) { g1n = r1 / 49; int p = r1 - g1n * 49; g1h = p / 7; g1w = p - g1h * 7; av1 = true; }
  }
  const float *wp0 = W, *wp1 = W;
  const bool wv0 = nc0 < Nc, wv1 = nc1 < Nc;
  if (WMODE == 0) {
    if (wv0) wp0 = W + (size_t)nc0 * K + kbase;
    if (wv1) wp1 = W + (size_t)nc1 * K + kbase;
  } else {
    if (wv0) wp0 = W + (size_t)nc0 * 9216;
    if (wv1) wp1 = W + (size_t)nc1 * 9216;
  }

  __hip_bfloat16* lwA0 = ldsA + s0 * 512 + sl * 8;
  __hip_bfloat16* lwA1 = lwA0 + 2048;
  __hip_bfloat16* lwB0 = ldsB + s0 * 512 + sl * 8;
  __hip_bfloat16* lwB1 = lwB0 + 2048;

  const int lane = t & 63, wv_ = t >> 6;
  const int wm = wv_ >> 1, wn = wv_ & 1;
  const __hip_bfloat16* rA = ldsA + wm * 2048 + lane * 8;
  const __hip_bfloat16* rB = ldsB + wn * 2048 + lane * 8;

  f32x4 acc[4][4] = {};

  for (int kt = k0; kt < k0 + k_len; kt += 32) {
    bf16x8 va0 = {}, va1 = {}, vb0 = {}, vb1 = {};
    if (AMODE == 0) {
      if (av0) va0 = *(const bf16x8*)(ap0 + kt);
      if (av1) va1 = *(const bf16x8*)(ap1 + kt);
    } else {
      int kp = kt + kbase;
      int rs = kp >> 10, c = kp & 1023;
      int rr = rs / 3, ss = rs - rr * 3;
      if (av0) { int ih = g0h*2-1+rr, iw = g0w*2-1+ss;
        if ((unsigned)ih < 13u && (unsigned)iw < 13u)
          va0 = *(const bf16x8*)(A + ((size_t)(g0n*169 + ih*13 + iw))*1024 + c); }
      if (av1) { int ih = g1h*2-1+rr, iw = g1w*2-1+ss;
        if ((unsigned)ih < 13u && (unsigned)iw < 13u)
          va1 = *(const bf16x8*)(A + ((size_t)(g1n*169 + ih*13 + iw))*1024 + c); }
    }
    if (WMODE == 0) {
      if (wv0) { float4 a = *(const float4*)(wp0 + kt);
                 float4 b = *(const float4*)(wp0 + kt + 4); vb0 = cvt8(a, b); }
      if (wv1) { float4 a = *(const float4*)(wp1 + kt);
                 float4 b = *(const float4*)(wp1 + kt + 4); vb1 = cvt8(a, b); }
    } else {
      int kp = kt + kbase;
      int rs = kp >> 10, c = kp & 1023;
      if (wv0) { const float* p = wp0 + (size_t)c * 9 + rs;
#pragma unroll
        for (int j = 0; j < 8; j++) vb0[j] = f2bs(p[j * 9]); }
      if (wv1) { const float* p = wp1 + (size_t)c * 9 + rs;
#pragma unroll
        for (int j = 0; j < 8; j++) vb1[j] = f2bs(p[j * 9]); }
    }
    *(bf16x8*)lwA0 = va0;  *(bf16x8*)lwA1 = va1;
    *(bf16x8*)lwB0 = vb0;  *(bf16x8*)lwB1 = vb1;
    __syncthreads();
    bf16x8 af[4], bfr[4];
#pragma unroll
    for (int i = 0; i < 4; i++) af[i] = *(const bf16x8*)(rA + i * 512);
#pragma unroll
    for (int j = 0; j < 4; j++) bfr[j] = *(const bf16x8*)(rB + j * 512);
#pragma unroll
    for (int i = 0; i < 4; i++)
#pragma unroll
      for (int j = 0; j < 4; j++)
        acc[i][j] = __builtin_amdgcn_mfma_f32_16x16x32_bf16(af[i], bfr[j], acc[i][j], 0, 0, 0);
    __syncthreads();
  }

  // epilogue: C/D map col=lane&15, row=(lane>>4)*4+reg
  const int quad = lane >> 4, nl = lane & 15;
  float bv[4]; int cj[4]; bool cv[4];
#pragma unroll
  for (int j = 0; j < 4; j++) {
    cj[j] = bn + wn * 64 + j * 16 + nl;
    cv[j] = cj[j] < Nc;
    bv[j] = (EPI != 3 && cv[j]) ? bias[cj[j]] : 0.f;
  }
#pragma unroll
  for (int i = 0; i < 4; i++) {
#pragma unroll
    for (int r = 0; r < 4; r++) {
      int m = bm + wm * 64 + i * 16 + quad * 4 + r;
      if (m >= M) continue;
      int n = m / O_HW, p = m - n * O_HW;
      size_t orow = (size_t)(n * O_L + O_off + p);
#pragma unroll
      for (int j = 0; j < 4; j++) {
        if (!cv[j]) continue;
        float v = acc[i][j][r] + bv[j];
        if (EPI == 1) v = 1.f / (1.f + expf(-v));
        if (EPI == 2) v = fmaxf(v, 0.f);
        if (EPI == 0 || EPI == 1) ((float*)outv)[orow * Nc + cj[j]] = v;
        else if (EPI == 2) ((__hip_bfloat16*)outv)[orow * Nc + cj[j]] = __float2bfloat16(v);
        else if (EPI == 3) atomicAdd((float*)outv + orow * Nc + cj[j], acc[i][j][r]);
        else ((float*)outv)[((size_t)n * Nc + cj[j]) * O_HW + p] = v;
      }
    }
  }
}

// f32 NCHW [n][C][HW] -> bf16 channel-last [n][HW][C]
__global__ __launch_bounds__(256) void transpose_cl_k(const float* __restrict__ x,
    __hip_bfloat16* __restrict__ xt, int C, int HW)
{
  __shared__ float tile[32][33];
  int p0 = blockIdx.x * 32, c0 = blockIdx.y * 32, n = blockIdx.z;
  const float* xb = x + (size_t)n * C * HW;
  __hip_bfloat16* xtb = xt + (size_t)n * HW * C;
  int tx = threadIdx.x & 31, ty = threadIdx.x >> 5;
  for (int i = ty; i < 32; i += 8) {
    int c = c0 + i, p = p0 + tx;
    tile[i][tx] = (p < HW) ? xb[(size_t)c * HW + p] : 0.f;
  }
  __syncthreads();
  for (int i = ty; i < 32; i += 8) {
    int p = p0 + i, c = c0 + tx;
    if (p < HW) xtb[(size_t)p * C + c] = __float2bfloat16(tile[tx][i]);
  }
}

__global__ __launch_bounds__(256) void biasinit_k(float* __restrict__ src,
                                                  const float* __restrict__ bias)
{
  int blk = blockIdx.x;        // 0..97
  int n = blk / 49, p = blk - n * 49;
  src[((size_t)(n * LTOT + 13294 + p)) * 256 + threadIdx.x] = bias[threadIdx.x];
}

// x1 (N,256,50,50) -> src rows [10000,12500) f32 + srcb bf16
__global__ __launch_bounds__(256) void copy_lvl1_in_k(const float* __restrict__ x,
    float* __restrict__ src, __hip_bfloat16* __restrict__ srcb)
{
  __shared__ float tile[32][33];
  int p0 = blockIdx.x * 32, c0 = blockIdx.y * 32, n = blockIdx.z;
  int tx = threadIdx.x & 31, ty = threadIdx.x >> 5;
  for (int i = ty; i < 32; i += 8) {
    int c = c0 + i, p = p0 + tx;
    tile[i][tx] = (p < 2500) ? x[((size_t)n * 256 + c) * 2500 + p] : 0.f;
  }
  __syncthreads();
  for (int i = ty; i < 32; i += 8) {
    int p = p0 + i, c = c0 + tx;
    if (p < 2500) {
      float v = tile[tx][i];
      size_t a = ((size_t)(n * LTOT + 10000 + p)) * 256 + c;
      src[a] = v;
      srcb[a] = __float2bfloat16(v);
    }
  }
}

// h2 rows [10000,12500) f32 -> out1 (N,256,50,50) f32
__global__ __launch_bounds__(256) void copy_lvl1_out_k(const float* __restrict__ h2,
                                                       float* __restrict__ out)
{
  __shared__ float tile[32][33];
  int p0 = blockIdx.x * 32, c0 = blockIdx.y * 32, n = blockIdx.z;
  int tx = threadIdx.x & 31, ty = threadIdx.x >> 5;
  for (int i = ty; i < 32; i += 8) {
    int p = p0 + i, c = c0 + tx;
    tile[tx][i] = (p < 2500) ? h2[((size_t)(n * LTOT + 10000 + p)) * 256 + c] : 0.f;
  }
  __syncthreads();
  for (int i = ty; i < 32; i += 8) {
    int c = c0 + i, p = p0 + tx;
    if (p < 2500) out[((size_t)n * 256 + c) * 2500 + p] = tile[i][tx];
  }
}

// GroupNorm stats over conv levels {0,2,3,4}; 256 blocks = 4 lvl * 2 n * 32 grp
__global__ __launch_bounds__(256) void gn_stats_k(const float* __restrict__ src,
                                                  float* __restrict__ stats)
{
  const int offs[4] = {0, 12500, 13125, 13294};
  const int hws[4]  = {10000, 625, 169, 49};
  int b = blockIdx.x;
  int li = b >> 6, n = (b >> 5) & 1, g = b & 31;
  int off = offs[li], hw = hws[li];
  int cnt = hw * 8;
  float s = 0.f, s2 = 0.f;
  for (int i = threadIdx.x; i < cnt; i += 256) {
    int p = i >> 3, j = i & 7;
    float v = src[((size_t)(n * LTOT + off + p)) * 256 + g * 8 + j];
    s += v; s2 += v * v;
  }
  __shared__ float r1[4], r2[4];
  for (int o = 32; o; o >>= 1) { s += __shfl_down(s, o, 64); s2 += __shfl_down(s2, o, 64); }
  int t = threadIdx.x;
  if ((t & 63) == 0) { r1[t >> 6] = s; r2[t >> 6] = s2; }
  __syncthreads();
  if (t == 0) {
    float S = r1[0] + r1[1] + r1[2] + r1[3];
    float S2 = r2[0] + r2[1] + r2[2] + r2[3];
    float mean = S / (float)cnt;
    float var = S2 / (float)cnt - mean * mean;
    int si = (li * 2 + n) * 32 + g;
    stats[si * 2] = mean;
    stats[si * 2 + 1] = rsqrtf(var + 1e-5f);
  }
}

__global__ __launch_bounds__(256) void gn_apply_k(float* __restrict__ src,
    __hip_bfloat16* __restrict__ srcb,
    const float* __restrict__ stats, const float* __restrict__ g,
    const float* __restrict__ b, int off, int hw, int li)
{
  int blk = blockIdx.x;
  int n = blk / hw, p = blk - n * hw;
  int t = threadIdx.x;
  int si = (li * 2 + n) * 32 + (t >> 3);
  float mean = stats[si * 2], rstd = stats[si * 2 + 1];
  size_t a = ((size_t)(n * LTOT + off + p)) * 256 + t;
  float v = (src[a] - mean) * rstd * g[t] + b[t];
  src[a] = v;
  srcb[a] = __float2bfloat16(v);
}

__global__ __launch_bounds__(256) void softmax20_k(float* __restrict__ aw, int total)
{
  int i = blockIdx.x * 256 + threadIdx.x;
  if (i >= total) return;
  float* p = aw + (size_t)(i >> 3) * 160 + (i & 7) * 20;
  float m = p[0];
#pragma unroll
  for (int j = 1; j < 20; j++) m = fmaxf(m, p[j]);
  float e[20], s = 0.f;
#pragma unroll
  for (int j = 0; j < 20; j++) { e[j] = expf(p[j] - m); s += e[j]; }
  float inv = 1.f / s;
#pragma unroll
  for (int j = 0; j < 20; j++) p[j] = e[j] * inv;
}

__device__ __forceinline__ float corner_val(const float* __restrict__ vlvl,
                                            int ix, int iy, int W, float w)
{
  bool valid = (ix >= 0) && (ix < W) && (iy >= 0) && (iy < W);
  int cx = min(max(ix, 0), W - 1), cy = min(max(iy, 0), W - 1);
  float v = vlvl[(size_t)(cy * W + cx) * 256];
  return valid ? v * w : 0.f;
}

// deformable sampling; block = one (n,q), thread = (head h, dim d); bf16 out
__global__ __launch_bounds__(256) void msdeform_k(const float* __restrict__ value,
    const float* __restrict__ offb, const float* __restrict__ awb,
    const float* __restrict__ refb, __hip_bfloat16* __restrict__ out)
{
  const int Wl[5]   = {100, 50, 25, 13, 7};
  const int lvlo[5] = {0, 10000, 12500, 13125, 13294};
  int q = blockIdx.x;
  int n = q / LTOT;
  int t = threadIdx.x;
  int h = t >> 5, d = t & 31;
  __shared__ float s_off[320], s_aw[160], s_ref[10];
  {
    const float* orow = offb + (size_t)q * 320;
    const float* arow = awb + (size_t)q * 160;
    const float* rrow = refb + (size_t)q * 10;
    for (int i = t; i < 320; i += 256) s_off[i] = orow[i];
    if (t < 160) s_aw[t] = arow[t];
    if (t < 10)  s_ref[t] = rrow[t];
  }
  __syncthreads();
  float acc = 0.f;
  const float* vbase = value + (size_t)n * LTOT * 256 + h * 32 + d;
#pragma unroll
  for (int l = 0; l < 5; l++) {
    int W = Wl[l];
    float fW = (float)W;
    float rx = s_ref[l * 2], ry = s_ref[l * 2 + 1];
    const float* vlvl = vbase + (size_t)lvlo[l] * 256;
#pragma unroll
    for (int pp = 0; pp < 4; pp++) {
      int oi = ((h * 5 + l) * 4 + pp) * 2;
      float lx = rx + s_off[oi] / fW;
      float ly = ry + s_off[oi + 1] / fW;
      float wgt = s_aw[h * 20 + l * 4 + pp];
      float x = lx * fW - 0.5f, y = ly * fW - 0.5f;
      float x0f = floorf(x), y0f = floorf(y);
      float wx = x - x0f, wy = y - y0f;
      int x0 = (int)x0f, y0 = (int)y0f;
      float s = corner_val(vlvl, x0,     y0,     W, (1.f - wx) * (1.f - wy))
              + corner_val(vlvl, x0 + 1, y0,     W, wx * (1.f - wy))
              + corner_val(vlvl, x0,     y0 + 1, W, (1.f - wx) * wy)
              + corner_val(vlvl, x0 + 1, y0 + 1, W, wx * wy);
      acc += wgt * s;
    }
  }
  out[(size_t)q * 256 + t] = __float2bfloat16(acc);
}

// y = LayerNorm(a + y); writes f32 y and bf16 yb
__global__ __launch_bounds__(256) void ln_resid_k(const float* __restrict__ a,
    float* __restrict__ y, __hip_bfloat16* __restrict__ yb,
    const float* __restrict__ g, const float* __restrict__ b)
{
  __shared__ float red[4];
  int row = blockIdx.x, t = threadIdx.x;
  size_t idx = (size_t)row * 256 + t;
  float v = a[idx] + y[idx];
  float s = v;
  for (int o = 32; o; o >>= 1) s += __shfl_down(s, o, 64);
  if ((t & 63) == 0) red[t >> 6] = s;
  __syncthreads();
  float mean = (red[0] + red[1] + red[2] + red[3]) * (1.f / 256.f);
  __syncthreads();
  float d = v - mean;
  float s2 = d * d;
  for (int o = 32; o; o >>= 1) s2 += __shfl_down(s2, o, 64);
  if ((t & 63) == 0) red[t >> 6] = s2;
  __syncthreads();
  float var = (red[0] + red[1] + red[2] + red[3]) * (1.f / 256.f);
  float rstd = rsqrtf(var + 1e-5f);
  float r = d * rstd * g[t] + b[t];
  y[idx] = r;
  yb[idx] = __float2bfloat16(r);
}

extern "C" void kernel_launch(void* const* d_in, const int* in_sizes, int n_in,
                              void* d_out, int out_size, void* d_ws, size_t ws_size,
                              hipStream_t stream)
{
  const float* x0    = (const float*)d_in[0];
  const float* x1    = (const float*)d_in[1];
  const float* x2    = (const float*)d_in[2];
  const float* x3    = (const float*)d_in[3];
  const float* W_ref = (const float*)d_in[4];
  const float* b_ref = (const float*)d_in[5];
  const float* W_off = (const float*)d_in[6];
  const float* b_off = (const float*)d_in[7];
  const float* W_aw  = (const float*)d_in[8];
  const float* b_aw  = (const float*)d_in[9];
  const float* W_val = (const float*)d_in[10];
  const float* b_val = (const float*)d_in[11];
  const float* W_outp= (const float*)d_in[12];
  const float* b_outp= (const float*)d_in[13];
  const float* gn_g  = (const float*)d_in[14];
  const float* gn_b  = (const float*)d_in[15];
  const float* Wc1   = (const float*)d_in[16];
  const float* bc1   = (const float*)d_in[17];
  const float* Wc2   = (const float*)d_in[18];
  const float* bc2   = (const float*)d_in[19];
  const float* Wc3   = (const float*)d_in[20];
  const float* bc3   = (const float*)d_in[21];
  const float* Wc4   = (const float*)d_in[22];
  const float* bc4   = (const float*)d_in[23];
  const float* Wc11  = (const float*)d_in[24];
  const float* bc11  = (const float*)d_in[25];
  const float* Wc22  = (const float*)d_in[26];
  const float* bc22  = (const float*)d_in[27];
  const float* Wc33  = (const float*)d_in[28];
  const float* bc33  = (const float*)d_in[29];
  const float* ln1_g = (const float*)d_in[30];
  const float* ln1_b = (const float*)d_in[31];
  const float* W1    = (const float*)d_in[32];
  const float* b1f   = (const float*)d_in[33];
  const float* W2    = (const float*)d_in[34];
  const float* b2f_  = (const float*)d_in[35];
  const float* ln2_g = (const float*)d_in[36];
  const float* ln2_b = (const float*)d_in[37];

  // ---- workspace (byte offsets) ----
  char* wsb = (char*)d_ws;
  float* src             = (float*)(wsb + 0);              // 27.3 MB
  float* valb            = (float*)(wsb + 27326464);       // also h2 f32
  float* h1              = (float*)(wsb + 54652928);
  __hip_bfloat16* srcb   = (__hip_bfloat16*)(wsb + 81979392);
  __hip_bfloat16* h1b    = (__hip_bfloat16*)(wsb + 95642624);
  __hip_bfloat16* sampb  = (__hip_bfloat16*)(wsb + 109305856); // also h2b
  __hip_bfloat16* h2b    = sampb;
  __hip_bfloat16* midb   = (__hip_bfloat16*)(wsb + 122969088); // 54.7 MB region R
  float* offb            = (float*)(wsb + 122969088);          // overlay R (pre-FFN)
  float* awb             = offb + (size_t)NLQ * 320;
  float* refb            = awb + (size_t)NLQ * 160;
  __hip_bfloat16* xt0    = (__hip_bfloat16*)(wsb + 122969088); // overlay R (phase 1)
  __hip_bfloat16* xt2    = (__hip_bfloat16*)(wsb + 122969088 + 5120000);
  __hip_bfloat16* xt3    = (__hip_bfloat16*)(wsb + 122969088 + 6400000);
  float* stats           = (float*)(wsb + 177622016);
  const size_t needed = 177622016 + 2048;
  if (ws_size < needed) return;

  dim3 B(256);

  // ---- phase 1: transposes, convs, GN into src/srcb ----
  transpose_cl_k<<<dim3(313,4,2), B,0,stream>>>(x0, xt0, 128, 10000);
  transpose_cl_k<<<dim3(20,16,2), B,0,stream>>>(x2, xt2, 512, 625);
  transpose_cl_k<<<dim3(6,32,2),  B,0,stream>>>(x3, xt3, 1024, 169);
  mgemm_k<0,0,0><<<dim3(157,2),B,0,stream>>>(xt0, Wc1, bc1, src, 20000,256,128,128, 20000,0,0, 10000,LTOT,0);
  mgemm_k<0,0,0><<<dim3(10,2), B,0,stream>>>(xt2, Wc2, bc2, src, 1250,256,512,512, 1250,0,0, 625,LTOT,12500);
  mgemm_k<0,0,0><<<dim3(3,2),  B,0,stream>>>(xt3, Wc3, bc3, src, 338,256,1024,1024, 338,0,0, 169,LTOT,13125);
  biasinit_k<<<98,B,0,stream>>>(src, bc4);
  mgemm_k<1,3,1><<<dim3(1,2,32),B,0,stream>>>(xt3, Wc4, bc4, src, 98,256,9216,288, 0,0,0, 49,LTOT,13294);
  copy_lvl1_in_k<<<dim3(79,8,2),B,0,stream>>>(x1, src, srcb);
  gn_stats_k<<<256,B,0,stream>>>(src, stats);
  gn_apply_k<<<20000,B,0,stream>>>(src, srcb, stats, gn_g, gn_b, 0,     10000, 0);
  gn_apply_k<<<1250, B,0,stream>>>(src, srcb, stats, gn_g, gn_b, 12500, 625,   1);
  gn_apply_k<<<338,  B,0,stream>>>(src, srcb, stats, gn_g, gn_b, 13125, 169,   2);
  gn_apply_k<<<98,   B,0,stream>>>(src, srcb, stats, gn_g, gn_b, 13294, 49,    3);

  // ---- projections + sampling ----
  mgemm_k<0,0,0><<<dim3(209,2),B,0,stream>>>(srcb, W_val, b_val, valb, NLQ,256,256,256, NLQ,0,0, NLQ,0,0);
  mgemm_k<0,0,0><<<dim3(209,3),B,0,stream>>>(srcb, W_off, b_off, offb, NLQ,320,256,256, NLQ,0,0, NLQ,0,0);
  mgemm_k<0,0,0><<<dim3(209,2),B,0,stream>>>(srcb, W_aw,  b_aw,  awb,  NLQ,160,256,256, NLQ,0,0, NLQ,0,0);
  mgemm_k<0,1,0><<<dim3(209,1),B,0,stream>>>(srcb, W_ref, b_ref, refb, NLQ,10, 256,256, NLQ,0,0, NLQ,0,0);
  softmax20_k<<<834,B,0,stream>>>(awb, NLQ * 8);
  msdeform_k<<<NLQ,B,0,stream>>>(valb, offb, awb, refb, sampb);

  // ---- out-proj + LN1 ----
  mgemm_k<0,0,0><<<dim3(209,2),B,0,stream>>>(sampb, W_outp, b_outp, h1, NLQ,256,256,256, NLQ,0,0, NLQ,0,0);
  ln_resid_k<<<NLQ,B,0,stream>>>(src, h1, h1b, ln1_g, ln1_b);

  // ---- FFN + LN2 (h2 in valb) ----
  mgemm_k<0,2,0><<<dim3(209,8),B,0,stream>>>(h1b,  W1, b1f,  midb, NLQ,1024,256,256, NLQ,0,0, NLQ,0,0);
  mgemm_k<0,0,0><<<dim3(209,2),B,0,stream>>>(midb, W2, b2f_, valb, NLQ,256,1024,1024, NLQ,0,0, NLQ,0,0);
  ln_resid_k<<<NLQ,B,0,stream>>>(h1, valb, h2b, ln2_g, ln2_b);

  // ---- output convs / copies ----
  float* out = (float*)d_out;
  mgemm_k<0,4,0><<<dim3(157,1),B,0,stream>>>(h2b, Wc11, bc11, out,           20000,128,256,256, 10000,LTOT,0,   10000,0,0);
  copy_lvl1_out_k<<<dim3(79,8,2),B,0,stream>>>(valb, out + 2560000);
  mgemm_k<0,4,0><<<dim3(10,4), B,0,stream>>>(h2b, Wc22, bc22, out + 3840000, 1250,512,256,256,  625,LTOT,12500, 625,0,0);
  mgemm_k<0,4,0><<<dim3(3,8),  B,0,stream>>>(h2b, Wc33, bc33, out + 4480000, 338,1024,256,256,  169,LTOT,13125, 169,0,0);
}

// Round 4
// 808.465 us; speedup vs baseline: 2.3502x; 1.3158x over previous
//
#include <hip/hip_runtime.h>
#include <hip/hip_bf16.h>

// I/O f32. Internal: bf16 MFMA GEMMs + bf16 value/sampling (threshold 9.9e-2).
// Levels (100,100),(50,50),(25,25),(13,13),(7,7); offsets 0,10000,12500,13125,13294
#define LTOT 13343
#define NLQ  26686

typedef __attribute__((ext_vector_type(8))) short bf16x8;
typedef __attribute__((ext_vector_type(4))) float f32x4;

__device__ __forceinline__ short f2bs(float x) {
  __hip_bfloat16 h = __float2bfloat16(x);
  return __builtin_bit_cast(short, h);
}

// ---------------------------------------------------------------------------
// MFMA GEMM: out = epi(A(bf16) @ W^T + bias)
// 128x128 tile, K-step 32, 4 waves, 16x16x32 bf16 MFMA, 4x4 frags/wave.
// AMODE: 0 = bf16 rowmajor [row][K] w/ (A_HW,A_L,A_off) row map
//        1 = im2col 3x3 s2 p1 from xt3 [n][169][1024], K' = rs*1024+c
// EPI: 0 bias->f32 rowmap | 1 bias+sigmoid->f32 | 2 bias+relu->bf16 rowmap
//      3 atomicAdd f32 (k-split) | 4 bias->f32 NCHW | 6 bias->bf16 rowmap
// WMODE: 0 = bf16 W[Nc][K] k-contig | 1 = f32 conv4 W[nc][c*9+rs] remap
// ---------------------------------------------------------------------------
template<int AMODE, int EPI, int WMODE>
__global__ __launch_bounds__(256) void mgemm_k(
    const __hip_bfloat16* __restrict__ A, const void* __restrict__ Wv,
    const float* __restrict__ bias, void* __restrict__ outv,
    int M, int Nc, int K, int k_len,
    int A_HW, int A_L, int A_off,
    int O_HW, int O_L, int O_off)
{
  __shared__ __hip_bfloat16 ldsA[4096];   // 8 KB
  __shared__ __hip_bfloat16 ldsB[4096];   // 8 KB
  const int t = threadIdx.x;
  const int bm = blockIdx.x * 128, bn = blockIdx.y * 128;
  const int k0 = blockIdx.z * k_len;

  const int sl = t & 63;
  const int mloc = sl & 15;
  const int kbase = (sl >> 4) * 8;
  const int s0 = t >> 6;

  const int r0 = bm + s0 * 16 + mloc, r1 = r0 + 64;
  const int nc0 = bn + s0 * 16 + mloc, nc1 = nc0 + 64;

  const __hip_bfloat16 *ap0 = A, *ap1 = A;
  bool av0 = false, av1 = false;
  int g0n=0, g0h=0, g0w=0, g1n=0, g1h=0, g1w=0;
  if (AMODE == 0) {
    if (r0 < M) { int nn = r0 / A_HW, p = r0 - nn * A_HW;
      ap0 = A + (size_t)(nn * A_L + A_off + p) * K + kbase; av0 = true; }
    if (r1 < M) { int nn = r1 / A_HW, p = r1 - nn * A_HW;
      ap1 = A + (size_t)(nn * A_L + A_off + p) * K + kbase; av1 = true; }
  } else {
    if (r0 < M) { g0n = r0 / 49; int p = r0 - g0n * 49; g0h = p / 7; g0w = p - g0h * 7; av0 = true; }
    if (r1 < M) { g1n = r1 / 49; int p = r1 - g1n * 49; g1h = p / 7; g1w = p - g1h * 7; av1 = true; }
  }
  const bool wv0 = nc0 < Nc, wv1 = nc1 < Nc;
  const __hip_bfloat16 *wb0 = (const __hip_bfloat16*)Wv, *wb1 = wb0;
  const float *wf0 = (const float*)Wv, *wf1 = wf0;
  if (WMODE == 0) {
    if (wv0) wb0 = (const __hip_bfloat16*)Wv + (size_t)nc0 * K + kbase;
    if (wv1) wb1 = (const __hip_bfloat16*)Wv + (size_t)nc1 * K + kbase;
  } else {
    if (wv0) wf0 = (const float*)Wv + (size_t)nc0 * 9216;
    if (wv1) wf1 = (const float*)Wv + (size_t)nc1 * 9216;
  }

  __hip_bfloat16* lwA0 = ldsA + s0 * 512 + sl * 8;
  __hip_bfloat16* lwA1 = lwA0 + 2048;
  __hip_bfloat16* lwB0 = ldsB + s0 * 512 + sl * 8;
  __hip_bfloat16* lwB1 = lwB0 + 2048;

  const int lane = t & 63, wv_ = t >> 6;
  const int wm = wv_ >> 1, wn = wv_ & 1;
  const __hip_bfloat16* rA = ldsA + wm * 2048 + lane * 8;
  const __hip_bfloat16* rB = ldsB + wn * 2048 + lane * 8;

  f32x4 acc[4][4] = {};

  for (int kt = k0; kt < k0 + k_len; kt += 32) {
    bf16x8 va0 = {}, va1 = {}, vb0 = {}, vb1 = {};
    if (AMODE == 0) {
      if (av0) va0 = *(const bf16x8*)(ap0 + kt);
      if (av1) va1 = *(const bf16x8*)(ap1 + kt);
    } else {
      int kp = kt + kbase;
      int rs = kp >> 10, c = kp & 1023;
      int rr = rs / 3, ss = rs - rr * 3;
      if (av0) { int ih = g0h*2-1+rr, iw = g0w*2-1+ss;
        if ((unsigned)ih < 13u && (unsigned)iw < 13u)
          va0 = *(const bf16x8*)(A + ((size_t)(g0n*169 + ih*13 + iw))*1024 + c); }
      if (av1) { int ih = g1h*2-1+rr, iw = g1w*2-1+ss;
        if ((unsigned)ih < 13u && (unsigned)iw < 13u)
          va1 = *(const bf16x8*)(A + ((size_t)(g1n*169 + ih*13 + iw))*1024 + c); }
    }
    if (WMODE == 0) {
      if (wv0) vb0 = *(const bf16x8*)(wb0 + kt);
      if (wv1) vb1 = *(const bf16x8*)(wb1 + kt);
    } else {
      int kp = kt + kbase;
      int rs = kp >> 10, c = kp & 1023;
      if (wv0) { const float* p = wf0 + (size_t)c * 9 + rs;
#pragma unroll
        for (int j = 0; j < 8; j++) vb0[j] = f2bs(p[j * 9]); }
      if (wv1) { const float* p = wf1 + (size_t)c * 9 + rs;
#pragma unroll
        for (int j = 0; j < 8; j++) vb1[j] = f2bs(p[j * 9]); }
    }
    *(bf16x8*)lwA0 = va0;  *(bf16x8*)lwA1 = va1;
    *(bf16x8*)lwB0 = vb0;  *(bf16x8*)lwB1 = vb1;
    __syncthreads();
    bf16x8 af[4], bfr[4];
#pragma unroll
    for (int i = 0; i < 4; i++) af[i] = *(const bf16x8*)(rA + i * 512);
#pragma unroll
    for (int j = 0; j < 4; j++) bfr[j] = *(const bf16x8*)(rB + j * 512);
#pragma unroll
    for (int i = 0; i < 4; i++)
#pragma unroll
      for (int j = 0; j < 4; j++)
        acc[i][j] = __builtin_amdgcn_mfma_f32_16x16x32_bf16(af[i], bfr[j], acc[i][j], 0, 0, 0);
    __syncthreads();
  }

  // epilogue: C/D map col=lane&15, row=(lane>>4)*4+reg
  const int quad = lane >> 4, nl = lane & 15;
  float bv[4]; int cj[4]; bool cv[4];
#pragma unroll
  for (int j = 0; j < 4; j++) {
    cj[j] = bn + wn * 64 + j * 16 + nl;
    cv[j] = cj[j] < Nc;
    bv[j] = (EPI != 3 && cv[j]) ? bias[cj[j]] : 0.f;
  }
#pragma unroll
  for (int i = 0; i < 4; i++) {
#pragma unroll
    for (int r = 0; r < 4; r++) {
      int m = bm + wm * 64 + i * 16 + quad * 4 + r;
      if (m >= M) continue;
      int n = m / O_HW, p = m - n * O_HW;
      size_t orow = (size_t)(n * O_L + O_off + p);
#pragma unroll
      for (int j = 0; j < 4; j++) {
        if (!cv[j]) continue;
        float v = acc[i][j][r] + bv[j];
        if (EPI == 1) v = 1.f / (1.f + expf(-v));
        if (EPI == 2) v = fmaxf(v, 0.f);
        if (EPI == 0 || EPI == 1) ((float*)outv)[orow * Nc + cj[j]] = v;
        else if (EPI == 2 || EPI == 6) ((__hip_bfloat16*)outv)[orow * Nc + cj[j]] = __float2bfloat16(v);
        else if (EPI == 3) atomicAdd((float*)outv + orow * Nc + cj[j], acc[i][j][r]);
        else ((float*)outv)[((size_t)n * Nc + cj[j]) * O_HW + p] = v;
      }
    }
  }
}

// bulk f32 -> bf16 weight conversion (13 matrices)
struct CvtEnt { const float* s; __hip_bfloat16* d; int n; };
struct CvtTab { CvtEnt e[13]; };
__global__ __launch_bounds__(256) void cvt_weights_k(CvtTab tab)
{
  CvtEnt E = tab.e[blockIdx.y];
  int i = blockIdx.x * 256 + threadIdx.x;
  if (i < E.n) E.d[i] = __float2bfloat16(E.s[i]);
}

// f32 NCHW [n][C][HW] -> bf16 channel-last [n][HW][C]
__global__ __launch_bounds__(256) void transpose_cl_k(const float* __restrict__ x,
    __hip_bfloat16* __restrict__ xt, int C, int HW)
{
  __shared__ float tile[32][33];
  int p0 = blockIdx.x * 32, c0 = blockIdx.y * 32, n = blockIdx.z;
  const float* xb = x + (size_t)n * C * HW;
  __hip_bfloat16* xtb = xt + (size_t)n * HW * C;
  int tx = threadIdx.x & 31, ty = threadIdx.x >> 5;
  for (int i = ty; i < 32; i += 8) {
    int c = c0 + i, p = p0 + tx;
    tile[i][tx] = (p < HW) ? xb[(size_t)c * HW + p] : 0.f;
  }
  __syncthreads();
  for (int i = ty; i < 32; i += 8) {
    int p = p0 + i, c = c0 + tx;
    if (p < HW) xtb[(size_t)p * C + c] = __float2bfloat16(tile[tx][i]);
  }
}

__global__ __launch_bounds__(256) void biasinit_k(float* __restrict__ src,
                                                  const float* __restrict__ bias)
{
  int blk = blockIdx.x;        // 0..97
  int n = blk / 49, p = blk - n * 49;
  src[((size_t)(n * LTOT + 13294 + p)) * 256 + threadIdx.x] = bias[threadIdx.x];
}

// x1 (N,256,50,50) -> src rows [10000,12500) f32 + srcb bf16
__global__ __launch_bounds__(256) void copy_lvl1_in_k(const float* __restrict__ x,
    float* __restrict__ src, __hip_bfloat16* __restrict__ srcb)
{
  __shared__ float tile[32][33];
  int p0 = blockIdx.x * 32, c0 = blockIdx.y * 32, n = blockIdx.z;
  int tx = threadIdx.x & 31, ty = threadIdx.x >> 5;
  for (int i = ty; i < 32; i += 8) {
    int c = c0 + i, p = p0 + tx;
    tile[i][tx] = (p < 2500) ? x[((size_t)n * 256 + c) * 2500 + p] : 0.f;
  }
  __syncthreads();
  for (int i = ty; i < 32; i += 8) {
    int p = p0 + i, c = c0 + tx;
    if (p < 2500) {
      float v = tile[tx][i];
      size_t a = ((size_t)(n * LTOT + 10000 + p)) * 256 + c;
      src[a] = v;
      srcb[a] = __float2bfloat16(v);
    }
  }
}

// h2 rows [10000,12500) f32 -> out1 (N,256,50,50) f32
__global__ __launch_bounds__(256) void copy_lvl1_out_k(const float* __restrict__ h2,
                                                       float* __restrict__ out)
{
  __shared__ float tile[32][33];
  int p0 = blockIdx.x * 32, c0 = blockIdx.y * 32, n = blockIdx.z;
  int tx = threadIdx.x & 31, ty = threadIdx.x >> 5;
  for (int i = ty; i < 32; i += 8) {
    int p = p0 + i, c = c0 + tx;
    tile[tx][i] = (p < 2500) ? h2[((size_t)(n * LTOT + 10000 + p)) * 256 + c] : 0.f;
  }
  __syncthreads();
  for (int i = ty; i < 32; i += 8) {
    int c = c0 + i, p = p0 + tx;
    if (p < 2500) out[((size_t)n * 256 + c) * 2500 + p] = tile[i][tx];
  }
}

// GroupNorm stats over conv levels {0,2,3,4}; 256 blocks = 4 lvl * 2 n * 32 grp
__global__ __launch_bounds__(256) void gn_stats_k(const float* __restrict__ src,
                                                  float* __restrict__ stats)
{
  const int offs[4] = {0, 12500, 13125, 13294};
  const int hws[4]  = {10000, 625, 169, 49};
  int b = blockIdx.x;
  int li = b >> 6, n = (b >> 5) & 1, g = b & 31;
  int off = offs[li], hw = hws[li];
  int cnt = hw * 8;
  float s = 0.f, s2 = 0.f;
  for (int i = threadIdx.x; i < cnt; i += 256) {
    int p = i >> 3, j = i & 7;
    float v = src[((size_t)(n * LTOT + off + p)) * 256 + g * 8 + j];
    s += v; s2 += v * v;
  }
  __shared__ float r1[4], r2[4];
  for (int o = 32; o; o >>= 1) { s += __shfl_down(s, o, 64); s2 += __shfl_down(s2, o, 64); }
  int t = threadIdx.x;
  if ((t & 63) == 0) { r1[t >> 6] = s; r2[t >> 6] = s2; }
  __syncthreads();
  if (t == 0) {
    float S = r1[0] + r1[1] + r1[2] + r1[3];
    float S2 = r2[0] + r2[1] + r2[2] + r2[3];
    float mean = S / (float)cnt;
    float var = S2 / (float)cnt - mean * mean;
    int si = (li * 2 + n) * 32 + g;
    stats[si * 2] = mean;
    stats[si * 2 + 1] = rsqrtf(var + 1e-5f);
  }
}

__global__ __launch_bounds__(256) void gn_apply_k(float* __restrict__ src,
    __hip_bfloat16* __restrict__ srcb,
    const float* __restrict__ stats, const float* __restrict__ g,
    const float* __restrict__ b, int off, int hw, int li)
{
  int blk = blockIdx.x;
  int n = blk / hw, p = blk - n * hw;
  int t = threadIdx.x;
  int si = (li * 2 + n) * 32 + (t >> 3);
  float mean = stats[si * 2], rstd = stats[si * 2 + 1];
  size_t a = ((size_t)(n * LTOT + off + p)) * 256 + t;
  float v = (src[a] - mean) * rstd * g[t] + b[t];
  src[a] = v;
  srcb[a] = __float2bfloat16(v);
}

__global__ __launch_bounds__(256) void softmax20_k(float* __restrict__ aw, int total)
{
  int i = blockIdx.x * 256 + threadIdx.x;
  if (i >= total) return;
  float* p = aw + (size_t)(i >> 3) * 160 + (i & 7) * 20;
  float m = p[0];
#pragma unroll
  for (int j = 1; j < 20; j++) m = fmaxf(m, p[j]);
  float e[20], s = 0.f;
#pragma unroll
  for (int j = 0; j < 20; j++) { e[j] = expf(p[j] - m); s += e[j]; }
  float inv = 1.f / s;
#pragma unroll
  for (int j = 0; j < 20; j++) p[j] = e[j] * inv;
}

// deformable sampling, two-phase: 160 prep threads compute packed
// (element-offset, fused weight) per (head,point,corner) into LDS;
// then 256 threads do pure gather+FMA. value is bf16.
__global__ __launch_bounds__(256) void msdeform_k(const __hip_bfloat16* __restrict__ value,
    const float* __restrict__ offb, const float* __restrict__ awb,
    const float* __restrict__ refb, __hip_bfloat16* __restrict__ out)
{
  __shared__ int4 s_c[160][2];
  const int q = blockIdx.x;
  const int n = q / LTOT;
  const int t = threadIdx.x;
  if (t < 160) {
    const int Wl[5]   = {100, 50, 25, 13, 7};
    const int lvlo[5] = {0, 10000, 12500, 13125, 13294};
    int h = t / 20, pt = t - h * 20;     // pt = l*4+pp
    int l = pt >> 2;
    int W = Wl[l], lo = lvlo[l];
    float fW = (float)W;
    float rx = refb[(size_t)q * 10 + l * 2];
    float ry = refb[(size_t)q * 10 + l * 2 + 1];
    int oi = (h * 20 + pt) * 2;          // ((h*5+l)*4+pp)*2
    float ox = offb[(size_t)q * 320 + oi];
    float oy = offb[(size_t)q * 320 + oi + 1];
    float wgt = awb[(size_t)q * 160 + t];
    float x = (rx + ox / fW) * fW - 0.5f;
    float y = (ry + oy / fW) * fW - 0.5f;
    float x0f = floorf(x), y0f = floorf(y);
    float wx = x - x0f, wy = y - y0f;
    int x0 = (int)x0f, y0 = (int)y0f;
    int hb = h * 32;
    auto mk = [&](int ix, int iy, float w) {
      bool v = (ix >= 0) & (ix < W) & (iy >= 0) & (iy < W);
      int cx = min(max(ix, 0), W - 1), cy = min(max(iy, 0), W - 1);
      int off = (lo + cy * W + cx) * 256 + hb;
      float fw = v ? w * wgt : 0.f;
      return make_int2(off, __float_as_int(fw));
    };
    int2 c00 = mk(x0,     y0,     (1.f - wx) * (1.f - wy));
    int2 c10 = mk(x0 + 1, y0,     wx * (1.f - wy));
    int2 c01 = mk(x0,     y0 + 1, (1.f - wx) * wy);
    int2 c11 = mk(x0 + 1, y0 + 1, wx * wy);
    s_c[t][0] = make_int4(c00.x, c00.y, c10.x, c10.y);
    s_c[t][1] = make_int4(c01.x, c01.y, c11.x, c11.y);
  }
  __syncthreads();
  const int h = t >> 5, d = t & 31;
  const __hip_bfloat16* vb = value + (size_t)n * LTOT * 256 + d;
  float acc = 0.f;
#pragma unroll
  for (int p = 0; p < 20; p++) {
    int4 a = s_c[h * 20 + p][0];
    int4 b = s_c[h * 20 + p][1];
    acc += __bfloat162float(vb[a.x]) * __int_as_float(a.y);
    acc += __bfloat162float(vb[a.z]) * __int_as_float(a.w);
    acc += __bfloat162float(vb[b.x]) * __int_as_float(b.y);
    acc += __bfloat162float(vb[b.z]) * __int_as_float(b.w);
  }
  out[(size_t)q * 256 + t] = __float2bfloat16(acc);
}

// y = LayerNorm(a + y); writes f32 y and bf16 yb
__global__ __launch_bounds__(256) void ln_resid_k(const float* __restrict__ a,
    float* __restrict__ y, __hip_bfloat16* __restrict__ yb,
    const float* __restrict__ g, const float* __restrict__ b)
{
  __shared__ float red[4];
  int row = blockIdx.x, t = threadIdx.x;
  size_t idx = (size_t)row * 256 + t;
  float v = a[idx] + y[idx];
  float s = v;
  for (int o = 32; o; o >>= 1) s += __shfl_down(s, o, 64);
  if ((t & 63) == 0) red[t >> 6] = s;
  __syncthreads();
  float mean = (red[0] + red[1] + red[2] + red[3]) * (1.f / 256.f);
  __syncthreads();
  float d = v - mean;
  float s2 = d * d;
  for (int o = 32; o; o >>= 1) s2 += __shfl_down(s2, o, 64);
  if ((t & 63) == 0) red[t >> 6] = s2;
  __syncthreads();
  float var = (red[0] + red[1] + red[2] + red[3]) * (1.f / 256.f);
  float rstd = rsqrtf(var + 1e-5f);
  float r = d * rstd * g[t] + b[t];
  y[idx] = r;
  yb[idx] = __float2bfloat16(r);
}

extern "C" void kernel_launch(void* const* d_in, const int* in_sizes, int n_in,
                              void* d_out, int out_size, void* d_ws, size_t ws_size,
                              hipStream_t stream)
{
  const float* x0    = (const float*)d_in[0];
  const float* x1    = (const float*)d_in[1];
  const float* x2    = (const float*)d_in[2];
  const float* x3    = (const float*)d_in[3];
  const float* W_ref = (const float*)d_in[4];
  const float* b_ref = (const float*)d_in[5];
  const float* W_off = (const float*)d_in[6];
  const float* b_off = (const float*)d_in[7];
  const float* W_aw  = (const float*)d_in[8];
  const float* b_aw  = (const float*)d_in[9];
  const float* W_val = (const float*)d_in[10];
  const float* b_val = (const float*)d_in[11];
  const float* W_outp= (const float*)d_in[12];
  const float* b_outp= (const float*)d_in[13];
  const float* gn_g  = (const float*)d_in[14];
  const float* gn_b  = (const float*)d_in[15];
  const float* Wc1   = (const float*)d_in[16];
  const float* bc1   = (const float*)d_in[17];
  const float* Wc2   = (const float*)d_in[18];
  const float* bc2   = (const float*)d_in[19];
  const float* Wc3   = (const float*)d_in[20];
  const float* bc3   = (const float*)d_in[21];
  const float* Wc4   = (const float*)d_in[22];
  const float* bc4   = (const float*)d_in[23];
  const float* Wc11  = (const float*)d_in[24];
  const float* bc11  = (const float*)d_in[25];
  const float* Wc22  = (const float*)d_in[26];
  const float* bc22  = (const float*)d_in[27];
  const float* Wc33  = (const float*)d_in[28];
  const float* bc33  = (const float*)d_in[29];
  const float* ln1_g = (const float*)d_in[30];
  const float* ln1_b = (const float*)d_in[31];
  const float* W1    = (const float*)d_in[32];
  const float* b1f   = (const float*)d_in[33];
  const float* W2    = (const float*)d_in[34];
  const float* b2f_  = (const float*)d_in[35];
  const float* ln2_g = (const float*)d_in[36];
  const float* ln2_b = (const float*)d_in[37];

  // ---- workspace (byte offsets) ----
  char* wsb = (char*)d_ws;
  float* src             = (float*)(wsb + 0);              // 27.3 MB; later h2 f32
  __hip_bfloat16* valb   = (__hip_bfloat16*)(wsb + 27326464); // bf16 value, 13.7 MB
  __hip_bfloat16* warena = (__hip_bfloat16*)(wsb + 27326464 + 13663232); // 3.3 MB
  float* h1              = (float*)(wsb + 54652928);
  __hip_bfloat16* srcb   = (__hip_bfloat16*)(wsb + 81979392);
  __hip_bfloat16* h1b    = (__hip_bfloat16*)(wsb + 95642624);
  __hip_bfloat16* sampb  = (__hip_bfloat16*)(wsb + 109305856); // also h2b
  __hip_bfloat16* h2b    = sampb;
  __hip_bfloat16* midb   = (__hip_bfloat16*)(wsb + 122969088); // 54.7 MB region R
  float* offb            = (float*)(wsb + 122969088);          // overlay R (pre-FFN)
  float* awb             = offb + (size_t)NLQ * 320;
  float* refb            = awb + (size_t)NLQ * 160;
  __hip_bfloat16* xt0    = (__hip_bfloat16*)(wsb + 122969088); // overlay R (phase 1)
  __hip_bfloat16* xt2    = (__hip_bfloat16*)(wsb + 122969088 + 5120000);
  __hip_bfloat16* xt3    = (__hip_bfloat16*)(wsb + 122969088 + 6400000);
  float* stats           = (float*)(wsb + 177622016);
  const size_t needed = 177622016 + 2048;
  if (ws_size < needed) return;

  // bf16 weight arena offsets (elements)
  __hip_bfloat16* wW_val = warena + 0;
  __hip_bfloat16* wW_off = warena + 65536;
  __hip_bfloat16* wW_aw  = warena + 147456;
  __hip_bfloat16* wW_ref = warena + 188416;
  __hip_bfloat16* wW_out = warena + 190976;
  __hip_bfloat16* wW1    = warena + 256512;
  __hip_bfloat16* wW2    = warena + 518656;
  __hip_bfloat16* wWc1   = warena + 780800;
  __hip_bfloat16* wWc2   = warena + 813568;
  __hip_bfloat16* wWc3   = warena + 944640;
  __hip_bfloat16* wWc11  = warena + 1206784;
  __hip_bfloat16* wWc22  = warena + 1239552;
  __hip_bfloat16* wWc33  = warena + 1370624;

  dim3 B(256);

  // ---- weight conversion (13 matrices, max n = 262144 -> 1024 blocks) ----
  CvtTab tab = {{
    {W_val, wW_val, 65536}, {W_off, wW_off, 81920}, {W_aw, wW_aw, 40960},
    {W_ref, wW_ref, 2560},  {W_outp, wW_out, 65536},{W1, wW1, 262144},
    {W2, wW2, 262144},      {Wc1, wWc1, 32768},     {Wc2, wWc2, 131072},
    {Wc3, wWc3, 262144},    {Wc11, wWc11, 32768},   {Wc22, wWc22, 131072},
    {Wc33, wWc33, 262144}
  }};
  cvt_weights_k<<<dim3(1024,13),B,0,stream>>>(tab);

  // ---- phase 1: transposes, convs, GN into src/srcb ----
  transpose_cl_k<<<dim3(313,4,2), B,0,stream>>>(x0, xt0, 128, 10000);
  transpose_cl_k<<<dim3(20,16,2), B,0,stream>>>(x2, xt2, 512, 625);
  transpose_cl_k<<<dim3(6,32,2),  B,0,stream>>>(x3, xt3, 1024, 169);
  mgemm_k<0,0,0><<<dim3(157,2),B,0,stream>>>(xt0, wWc1, bc1, src, 20000,256,128,128, 20000,0,0, 10000,LTOT,0);
  mgemm_k<0,0,0><<<dim3(10,2), B,0,stream>>>(xt2, wWc2, bc2, src, 1250,256,512,512, 1250,0,0, 625,LTOT,12500);
  mgemm_k<0,0,0><<<dim3(3,2),  B,0,stream>>>(xt3, wWc3, bc3, src, 338,256,1024,1024, 338,0,0, 169,LTOT,13125);
  biasinit_k<<<98,B,0,stream>>>(src, bc4);
  mgemm_k<1,3,1><<<dim3(1,2,32),B,0,stream>>>(xt3, Wc4, bc4, src, 98,256,9216,288, 0,0,0, 49,LTOT,13294);
  copy_lvl1_in_k<<<dim3(79,8,2),B,0,stream>>>(x1, src, srcb);
  gn_stats_k<<<256,B,0,stream>>>(src, stats);
  gn_apply_k<<<20000,B,0,stream>>>(src, srcb, stats, gn_g, gn_b, 0,     10000, 0);
  gn_apply_k<<<1250, B,0,stream>>>(src, srcb, stats, gn_g, gn_b, 12500, 625,   1);
  gn_apply_k<<<338,  B,0,stream>>>(src, srcb, stats, gn_g, gn_b, 13125, 169,   2);
  gn_apply_k<<<98,   B,0,stream>>>(src, srcb, stats, gn_g, gn_b, 13294, 49,    3);

  // ---- projections + sampling ----
  mgemm_k<0,6,0><<<dim3(209,2),B,0,stream>>>(srcb, wW_val, b_val, valb, NLQ,256,256,256, NLQ,0,0, NLQ,0,0);
  mgemm_k<0,0,0><<<dim3(209,3),B,0,stream>>>(srcb, wW_off, b_off, offb, NLQ,320,256,256, NLQ,0,0, NLQ,0,0);
  mgemm_k<0,0,0><<<dim3(209,2),B,0,stream>>>(srcb, wW_aw,  b_aw,  awb,  NLQ,160,256,256, NLQ,0,0, NLQ,0,0);
  mgemm_k<0,1,0><<<dim3(209,1),B,0,stream>>>(srcb, wW_ref, b_ref, refb, NLQ,10, 256,256, NLQ,0,0, NLQ,0,0);
  softmax20_k<<<834,B,0,stream>>>(awb, NLQ * 8);
  msdeform_k<<<NLQ,B,0,stream>>>(valb, offb, awb, refb, sampb);

  // ---- out-proj + LN1 ----
  mgemm_k<0,0,0><<<dim3(209,2),B,0,stream>>>(sampb, wW_out, b_outp, h1, NLQ,256,256,256, NLQ,0,0, NLQ,0,0);
  ln_resid_k<<<NLQ,B,0,stream>>>(src, h1, h1b, ln1_g, ln1_b);

  // ---- FFN + LN2 (h2 f32 reuses src, dead after LN1) ----
  mgemm_k<0,2,0><<<dim3(209,8),B,0,stream>>>(h1b,  wW1, b1f,  midb, NLQ,1024,256,256, NLQ,0,0, NLQ,0,0);
  mgemm_k<0,0,0><<<dim3(209,2),B,0,stream>>>(midb, wW2, b2f_, src,  NLQ,256,1024,1024, NLQ,0,0, NLQ,0,0);
  ln_resid_k<<<NLQ,B,0,stream>>>(h1, src, h2b, ln2_g, ln2_b);

  // ---- output convs / copies ----
  float* out = (float*)d_out;
  mgemm_k<0,4,0><<<dim3(157,1),B,0,stream>>>(h2b, wWc11, bc11, out,           20000,128,256,256, 10000,LTOT,0,   10000,0,0);
  copy_lvl1_out_k<<<dim3(79,8,2),B,0,stream>>>(src, out + 2560000);
  mgemm_k<0,4,0><<<dim3(10,4), B,0,stream>>>(h2b, wWc22, bc22, out + 3840000, 1250,512,256,256,  625,LTOT,12500, 625,0,0);
  mgemm_k<0,4,0><<<dim3(3,8),  B,0,stream>>>(h2b, wWc33, bc33, out + 4480000, 338,1024,256,256,  169,LTOT,13125, 169,0,0);
}

// Round 5
// 699.801 us; speedup vs baseline: 2.7151x; 1.1553x over previous
//
#include <hip/hip_runtime.h>
#include <hip/hip_bf16.h>

// I/O f32. Internal: bf16 MFMA GEMMs + bf16 value/sampling (threshold 9.9e-2).
// Levels (100,100),(50,50),(25,25),(13,13),(7,7); offsets 0,10000,12500,13125,13294
#define LTOT 13343
#define NLQ  26686
// fixed workspace byte offsets (used inside EPI7 epilogue)
#define WS_VALB 27326464
#define WS_R    122969088

typedef __attribute__((ext_vector_type(8))) short bf16x8;
typedef __attribute__((ext_vector_type(4))) float f32x4;

__device__ __forceinline__ short f2bs(float x) {
  __hip_bfloat16 h = __float2bfloat16(x);
  return __builtin_bit_cast(short, h);
}

// ---------------------------------------------------------------------------
// MFMA GEMM: out = epi(A(bf16) @ W^T + bias)
// 128x128 tile, K-step 32, 4 waves, 16x16x32 bf16 MFMA, 4x4 frags/wave.
// AMODE: 0 = bf16 rowmajor [row][K] w/ (A_HW,A_L,A_off) row map
//        1 = im2col 3x3 s2 p1 from xt3 [n][169][1024], K' = rs*1024+c
// EPI: 0 bias->f32 rowmap | 1 bias+sigmoid->f32 | 2 bias+relu->bf16 rowmap
//      3 atomicAdd f32 | 4 bias->f32 NCHW | 6 bias->bf16 rowmap
//      7 fused projection: col<256 val->bf16, <576 off->f32, <736 aw->f32,
//        else ref->sigmoid f32 (outv = d_ws base)
// WMODE: 0 = bf16 W[Nc][K] k-contig | 1 = f32 conv4 W[nc][c*9+rs] remap
// ---------------------------------------------------------------------------
template<int AMODE, int EPI, int WMODE>
__global__ __launch_bounds__(256) void mgemm_k(
    const __hip_bfloat16* __restrict__ A, const void* __restrict__ Wv,
    const float* __restrict__ bias, void* __restrict__ outv,
    int M, int Nc, int K, int k_len,
    int A_HW, int A_L, int A_off,
    int O_HW, int O_L, int O_off)
{
  __shared__ __hip_bfloat16 ldsA[4096];   // 8 KB
  __shared__ __hip_bfloat16 ldsB[4096];   // 8 KB
  const int t = threadIdx.x;
  const int bm = blockIdx.x * 128, bn = blockIdx.y * 128;
  const int k0 = blockIdx.z * k_len;

  const int sl = t & 63;
  const int mloc = sl & 15;
  const int kbase = (sl >> 4) * 8;
  const int s0 = t >> 6;

  const int r0 = bm + s0 * 16 + mloc, r1 = r0 + 64;
  const int nc0 = bn + s0 * 16 + mloc, nc1 = nc0 + 64;

  const __hip_bfloat16 *ap0 = A, *ap1 = A;
  bool av0 = false, av1 = false;
  int g0n=0, g0h=0, g0w=0, g1n=0, g1h=0, g1w=0;
  if (AMODE == 0) {
    if (r0 < M) { int nn = r0 / A_HW, p = r0 - nn * A_HW;
      ap0 = A + (size_t)(nn * A_L + A_off + p) * K + kbase; av0 = true; }
    if (r1 < M) { int nn = r1 / A_HW, p = r1 - nn * A_HW;
      ap1 = A + (size_t)(nn * A_L + A_off + p) * K + kbase; av1 = true; }
  } else {
    if (r0 < M) { g0n = r0 / 49; int p = r0 - g0n * 49; g0h = p / 7; g0w = p - g0h * 7; av0 = true; }
    if (r1 < M) { g1n = r1 / 49; int p = r1 - g1n * 49; g1h = p / 7; g1w = p - g1h * 7; av1 = true; }
  }
  const bool wv0 = nc0 < Nc, wv1 = nc1 < Nc;
  const __hip_bfloat16 *wb0 = (const __hip_bfloat16*)Wv, *wb1 = wb0;
  const float *wf0 = (const float*)Wv, *wf1 = wf0;
  if (WMODE == 0) {
    if (wv0) wb0 = (const __hip_bfloat16*)Wv + (size_t)nc0 * K + kbase;
    if (wv1) wb1 = (const __hip_bfloat16*)Wv + (size_t)nc1 * K + kbase;
  } else {
    if (wv0) wf0 = (const float*)Wv + (size_t)nc0 * 9216;
    if (wv1) wf1 = (const float*)Wv + (size_t)nc1 * 9216;
  }

  __hip_bfloat16* lwA0 = ldsA + s0 * 512 + sl * 8;
  __hip_bfloat16* lwA1 = lwA0 + 2048;
  __hip_bfloat16* lwB0 = ldsB + s0 * 512 + sl * 8;
  __hip_bfloat16* lwB1 = lwB0 + 2048;

  const int lane = t & 63, wv_ = t >> 6;
  const int wm = wv_ >> 1, wn = wv_ & 1;
  const __hip_bfloat16* rA = ldsA + wm * 2048 + lane * 8;
  const __hip_bfloat16* rB = ldsB + wn * 2048 + lane * 8;

  f32x4 acc[4][4] = {};

  for (int kt = k0; kt < k0 + k_len; kt += 32) {
    bf16x8 va0 = {}, va1 = {}, vb0 = {}, vb1 = {};
    if (AMODE == 0) {
      if (av0) va0 = *(const bf16x8*)(ap0 + kt);
      if (av1) va1 = *(const bf16x8*)(ap1 + kt);
    } else {
      int kp = kt + kbase;
      int rs = kp >> 10, c = kp & 1023;
      int rr = rs / 3, ss = rs - rr * 3;
      if (av0) { int ih = g0h*2-1+rr, iw = g0w*2-1+ss;
        if ((unsigned)ih < 13u && (unsigned)iw < 13u)
          va0 = *(const bf16x8*)(A + ((size_t)(g0n*169 + ih*13 + iw))*1024 + c); }
      if (av1) { int ih = g1h*2-1+rr, iw = g1w*2-1+ss;
        if ((unsigned)ih < 13u && (unsigned)iw < 13u)
          va1 = *(const bf16x8*)(A + ((size_t)(g1n*169 + ih*13 + iw))*1024 + c); }
    }
    if (WMODE == 0) {
      if (wv0) vb0 = *(const bf16x8*)(wb0 + kt);
      if (wv1) vb1 = *(const bf16x8*)(wb1 + kt);
    } else {
      int kp = kt + kbase;
      int rs = kp >> 10, c = kp & 1023;
      if (wv0) { const float* p = wf0 + (size_t)c * 9 + rs;
#pragma unroll
        for (int j = 0; j < 8; j++) vb0[j] = f2bs(p[j * 9]); }
      if (wv1) { const float* p = wf1 + (size_t)c * 9 + rs;
#pragma unroll
        for (int j = 0; j < 8; j++) vb1[j] = f2bs(p[j * 9]); }
    }
    *(bf16x8*)lwA0 = va0;  *(bf16x8*)lwA1 = va1;
    *(bf16x8*)lwB0 = vb0;  *(bf16x8*)lwB1 = vb1;
    __syncthreads();
    bf16x8 af[4], bfr[4];
#pragma unroll
    for (int i = 0; i < 4; i++) af[i] = *(const bf16x8*)(rA + i * 512);
#pragma unroll
    for (int j = 0; j < 4; j++) bfr[j] = *(const bf16x8*)(rB + j * 512);
#pragma unroll
    for (int i = 0; i < 4; i++)
#pragma unroll
      for (int j = 0; j < 4; j++)
        acc[i][j] = __builtin_amdgcn_mfma_f32_16x16x32_bf16(af[i], bfr[j], acc[i][j], 0, 0, 0);
    __syncthreads();
  }

  // epilogue: C/D map col=lane&15, row=(lane>>4)*4+reg
  const int quad = lane >> 4, nl = lane & 15;
  float bv[4]; int cj[4]; bool cv[4];
#pragma unroll
  for (int j = 0; j < 4; j++) {
    cj[j] = bn + wn * 64 + j * 16 + nl;
    cv[j] = cj[j] < Nc;
    bv[j] = (EPI != 3 && cv[j]) ? bias[cj[j]] : 0.f;
  }
#pragma unroll
  for (int i = 0; i < 4; i++) {
#pragma unroll
    for (int r = 0; r < 4; r++) {
      int m = bm + wm * 64 + i * 16 + quad * 4 + r;
      if (m >= M) continue;
      int n = m / O_HW, p = m - n * O_HW;
      size_t orow = (size_t)(n * O_L + O_off + p);
#pragma unroll
      for (int j = 0; j < 4; j++) {
        if (!cv[j]) continue;
        float v = acc[i][j][r] + bv[j];
        if (EPI == 1) v = 1.f / (1.f + expf(-v));
        if (EPI == 2) v = fmaxf(v, 0.f);
        if (EPI == 0 || EPI == 1) ((float*)outv)[orow * Nc + cj[j]] = v;
        else if (EPI == 2 || EPI == 6) ((__hip_bfloat16*)outv)[orow * Nc + cj[j]] = __float2bfloat16(v);
        else if (EPI == 3) atomicAdd((float*)outv + orow * Nc + cj[j], acc[i][j][r]);
        else if (EPI == 7) {
          char* base = (char*)outv;
          int q = m, c = cj[j];
          if (c < 256)
            ((__hip_bfloat16*)(base + WS_VALB))[(size_t)q * 256 + c] = __float2bfloat16(v);
          else if (c < 576)
            ((float*)(base + WS_R))[(size_t)q * 320 + (c - 256)] = v;
          else if (c < 736)
            ((float*)(base + WS_R) + (size_t)NLQ * 320)[(size_t)q * 160 + (c - 576)] = v;
          else {
            float sv = 1.f / (1.f + expf(-v));
            ((float*)(base + WS_R) + (size_t)NLQ * 480)[(size_t)q * 10 + (c - 736)] = sv;
          }
        }
        else ((float*)outv)[((size_t)n * Nc + cj[j]) * O_HW + p] = v;
      }
    }
  }
}

// bulk f32 -> bf16 weight conversion (13 matrices)
struct CvtEnt { const float* s; __hip_bfloat16* d; int n; };
struct CvtTab { CvtEnt e[13]; };
__global__ __launch_bounds__(256) void cvt_weights_k(CvtTab tab)
{
  CvtEnt E = tab.e[blockIdx.y];
  int i = blockIdx.x * 256 + threadIdx.x;
  if (i < E.n) E.d[i] = __float2bfloat16(E.s[i]);
}

// concat f32 projection biases into one 746-float buffer
__global__ __launch_bounds__(256) void cat_bias_k(const float* __restrict__ bv,
    const float* __restrict__ bo, const float* __restrict__ ba,
    const float* __restrict__ br, float* __restrict__ dst)
{
  int i = blockIdx.x * 256 + threadIdx.x;
  if (i >= 746) return;
  float v;
  if (i < 256) v = bv[i];
  else if (i < 576) v = bo[i - 256];
  else if (i < 736) v = ba[i - 576];
  else v = br[i - 736];
  dst[i] = v;
}

// f32 NCHW [n][C][HW] -> bf16 channel-last [n][HW][C]
__global__ __launch_bounds__(256) void transpose_cl_k(const float* __restrict__ x,
    __hip_bfloat16* __restrict__ xt, int C, int HW)
{
  __shared__ float tile[32][33];
  int p0 = blockIdx.x * 32, c0 = blockIdx.y * 32, n = blockIdx.z;
  const float* xb = x + (size_t)n * C * HW;
  __hip_bfloat16* xtb = xt + (size_t)n * HW * C;
  int tx = threadIdx.x & 31, ty = threadIdx.x >> 5;
  for (int i = ty; i < 32; i += 8) {
    int c = c0 + i, p = p0 + tx;
    tile[i][tx] = (p < HW) ? xb[(size_t)c * HW + p] : 0.f;
  }
  __syncthreads();
  for (int i = ty; i < 32; i += 8) {
    int p = p0 + i, c = c0 + tx;
    if (p < HW) xtb[(size_t)p * C + c] = __float2bfloat16(tile[tx][i]);
  }
}

__global__ __launch_bounds__(256) void biasinit_k(float* __restrict__ src,
                                                  const float* __restrict__ bias)
{
  int blk = blockIdx.x;        // 0..97
  int n = blk / 49, p = blk - n * 49;
  src[((size_t)(n * LTOT + 13294 + p)) * 256 + threadIdx.x] = bias[threadIdx.x];
}

// x1 (N,256,50,50) -> src rows [10000,12500) f32 + srcb bf16
__global__ __launch_bounds__(256) void copy_lvl1_in_k(const float* __restrict__ x,
    float* __restrict__ src, __hip_bfloat16* __restrict__ srcb)
{
  __shared__ float tile[32][33];
  int p0 = blockIdx.x * 32, c0 = blockIdx.y * 32, n = blockIdx.z;
  int tx = threadIdx.x & 31, ty = threadIdx.x >> 5;
  for (int i = ty; i < 32; i += 8) {
    int c = c0 + i, p = p0 + tx;
    tile[i][tx] = (p < 2500) ? x[((size_t)n * 256 + c) * 2500 + p] : 0.f;
  }
  __syncthreads();
  for (int i = ty; i < 32; i += 8) {
    int p = p0 + i, c = c0 + tx;
    if (p < 2500) {
      float v = tile[tx][i];
      size_t a = ((size_t)(n * LTOT + 10000 + p)) * 256 + c;
      src[a] = v;
      srcb[a] = __float2bfloat16(v);
    }
  }
}

// h2 rows [10000,12500) f32 -> out1 (N,256,50,50) f32
__global__ __launch_bounds__(256) void copy_lvl1_out_k(const float* __restrict__ h2,
                                                       float* __restrict__ out)
{
  __shared__ float tile[32][33];
  int p0 = blockIdx.x * 32, c0 = blockIdx.y * 32, n = blockIdx.z;
  int tx = threadIdx.x & 31, ty = threadIdx.x >> 5;
  for (int i = ty; i < 32; i += 8) {
    int p = p0 + i, c = c0 + tx;
    tile[tx][i] = (p < 2500) ? h2[((size_t)(n * LTOT + 10000 + p)) * 256 + c] : 0.f;
  }
  __syncthreads();
  for (int i = ty; i < 32; i += 8) {
    int c = c0 + i, p = p0 + tx;
    if (p < 2500) out[((size_t)n * 256 + c) * 2500 + p] = tile[i][tx];
  }
}

// GroupNorm raw sums, coalesced full-row reads; atomics into stats[64g][2]
// grid (171, 2): level-aligned 64-row chunks
__global__ __launch_bounds__(256) void gn_stats_k(const float* __restrict__ src,
                                                  float* __restrict__ stats)
{
  int b = blockIdx.x, n = blockIdx.y, t = threadIdx.x;
  int li, off, rr0, rend;
  if (b < 157)      { li = 0; off = 0;     rr0 = b * 64;         rend = min(rr0 + 64, 10000); }
  else if (b < 167) { li = 1; off = 12500; rr0 = (b - 157) * 64; rend = min(rr0 + 64, 625); }
  else if (b < 170) { li = 2; off = 13125; rr0 = (b - 167) * 64; rend = min(rr0 + 64, 169); }
  else              { li = 3; off = 13294; rr0 = 0;              rend = 49; }
  const float* base = src + ((size_t)(n * LTOT + off)) * 256 + t;
  float s = 0.f, s2 = 0.f;
  for (int r = rr0; r < rend; r++) {
    float v = base[(size_t)r * 256];
    s += v; s2 += v * v;
  }
  // reduce 8 consecutive lanes (one channel group)
  s  += __shfl_down(s, 4, 64);  s2 += __shfl_down(s2, 4, 64);
  s  += __shfl_down(s, 2, 64);  s2 += __shfl_down(s2, 2, 64);
  s  += __shfl_down(s, 1, 64);  s2 += __shfl_down(s2, 1, 64);
  if ((t & 7) == 0) {
    int g = t >> 3;
    int si = (li * 2 + n) * 32 + g;
    atomicAdd(&stats[si * 2],     s);
    atomicAdd(&stats[si * 2 + 1], s2);
  }
}

// merged GN apply + finalize; grid 21686 blocks = 2n * 10843 conv rows
__global__ __launch_bounds__(256) void gn_apply_k(float* __restrict__ src,
    __hip_bfloat16* __restrict__ srcb,
    const float* __restrict__ stats, const float* __restrict__ g,
    const float* __restrict__ b)
{
  int x = blockIdx.x;
  int n = x / 10843, cidx = x - n * 10843;
  int li, off, hw, p;
  if (cidx < 10000)      { li = 0; off = 0;     hw = 10000; p = cidx; }
  else if (cidx < 10625) { li = 1; off = 12500; hw = 625;   p = cidx - 10000; }
  else if (cidx < 10794) { li = 2; off = 13125; hw = 169;   p = cidx - 10625; }
  else                   { li = 3; off = 13294; hw = 49;    p = cidx - 10794; }
  int t = threadIdx.x;
  int si = (li * 2 + n) * 32 + (t >> 3);
  float cnt = (float)(hw * 8);
  float mean = stats[si * 2] / cnt;
  float var = stats[si * 2 + 1] / cnt - mean * mean;
  float rstd = rsqrtf(var + 1e-5f);
  size_t a = ((size_t)(n * LTOT + off + p)) * 256 + t;
  float v = (src[a] - mean) * rstd * g[t] + b[t];
  src[a] = v;
  srcb[a] = __float2bfloat16(v);
}

__global__ __launch_bounds__(256) void softmax20_k(float* __restrict__ aw, int total)
{
  int i = blockIdx.x * 256 + threadIdx.x;
  if (i >= total) return;
  float* p = aw + (size_t)(i >> 3) * 160 + (i & 7) * 20;
  float m = p[0];
#pragma unroll
  for (int j = 1; j < 20; j++) m = fmaxf(m, p[j]);
  float e[20], s = 0.f;
#pragma unroll
  for (int j = 0; j < 20; j++) { e[j] = expf(p[j] - m); s += e[j]; }
  float inv = 1.f / s;
#pragma unroll
  for (int j = 0; j < 20; j++) p[j] = e[j] * inv;
}

// deformable sampling, two-phase prep->gather; value bf16
__global__ __launch_bounds__(256) void msdeform_k(const __hip_bfloat16* __restrict__ value,
    const float* __restrict__ offb, const float* __restrict__ awb,
    const float* __restrict__ refb, __hip_bfloat16* __restrict__ out)
{
  __shared__ int4 s_c[160][2];
  const int q = blockIdx.x;
  const int n = q / LTOT;
  const int t = threadIdx.x;
  if (t < 160) {
    const int Wl[5]   = {100, 50, 25, 13, 7};
    const int lvlo[5] = {0, 10000, 12500, 13125, 13294};
    int h = t / 20, pt = t - h * 20;     // pt = l*4+pp
    int l = pt >> 2;
    int W = Wl[l], lo = lvlo[l];
    float fW = (float)W;
    float rx = refb[(size_t)q * 10 + l * 2];
    float ry = refb[(size_t)q * 10 + l * 2 + 1];
    int oi = (h * 20 + pt) * 2;
    float ox = offb[(size_t)q * 320 + oi];
    float oy = offb[(size_t)q * 320 + oi + 1];
    float wgt = awb[(size_t)q * 160 + t];
    float x = (rx + ox / fW) * fW - 0.5f;
    float y = (ry + oy / fW) * fW - 0.5f;
    float x0f = floorf(x), y0f = floorf(y);
    float wx = x - x0f, wy = y - y0f;
    int x0 = (int)x0f, y0 = (int)y0f;
    int hb = h * 32;
    auto mk = [&](int ix, int iy, float w) {
      bool v = (ix >= 0) & (ix < W) & (iy >= 0) & (iy < W);
      int cx = min(max(ix, 0), W - 1), cy = min(max(iy, 0), W - 1);
      int off = (lo + cy * W + cx) * 256 + hb;
      float fw = v ? w * wgt : 0.f;
      return make_int2(off, __float_as_int(fw));
    };
    int2 c00 = mk(x0,     y0,     (1.f - wx) * (1.f - wy));
    int2 c10 = mk(x0 + 1, y0,     wx * (1.f - wy));
    int2 c01 = mk(x0,     y0 + 1, (1.f - wx) * wy);
    int2 c11 = mk(x0 + 1, y0 + 1, wx * wy);
    s_c[t][0] = make_int4(c00.x, c00.y, c10.x, c10.y);
    s_c[t][1] = make_int4(c01.x, c01.y, c11.x, c11.y);
  }
  __syncthreads();
  const int h = t >> 5, d = t & 31;
  const __hip_bfloat16* vb = value + (size_t)n * LTOT * 256 + d;
  float acc = 0.f;
#pragma unroll
  for (int p = 0; p < 20; p++) {
    int4 a = s_c[h * 20 + p][0];
    int4 b = s_c[h * 20 + p][1];
    acc += __bfloat162float(vb[a.x]) * __int_as_float(a.y);
    acc += __bfloat162float(vb[a.z]) * __int_as_float(a.w);
    acc += __bfloat162float(vb[b.x]) * __int_as_float(b.y);
    acc += __bfloat162float(vb[b.z]) * __int_as_float(b.w);
  }
  out[(size_t)q * 256 + t] = __float2bfloat16(acc);
}

// y = LayerNorm(a + y); writes f32 y and bf16 yb
__global__ __launch_bounds__(256) void ln_resid_k(const float* __restrict__ a,
    float* __restrict__ y, __hip_bfloat16* __restrict__ yb,
    const float* __restrict__ g, const float* __restrict__ b)
{
  __shared__ float red[4];
  int row = blockIdx.x, t = threadIdx.x;
  size_t idx = (size_t)row * 256 + t;
  float v = a[idx] + y[idx];
  float s = v;
  for (int o = 32; o; o >>= 1) s += __shfl_down(s, o, 64);
  if ((t & 63) == 0) red[t >> 6] = s;
  __syncthreads();
  float mean = (red[0] + red[1] + red[2] + red[3]) * (1.f / 256.f);
  __syncthreads();
  float d = v - mean;
  float s2 = d * d;
  for (int o = 32; o; o >>= 1) s2 += __shfl_down(s2, o, 64);
  if ((t & 63) == 0) red[t >> 6] = s2;
  __syncthreads();
  float var = (red[0] + red[1] + red[2] + red[3]) * (1.f / 256.f);
  float rstd = rsqrtf(var + 1e-5f);
  float r = d * rstd * g[t] + b[t];
  y[idx] = r;
  yb[idx] = __float2bfloat16(r);
}

extern "C" void kernel_launch(void* const* d_in, const int* in_sizes, int n_in,
                              void* d_out, int out_size, void* d_ws, size_t ws_size,
                              hipStream_t stream)
{
  const float* x0    = (const float*)d_in[0];
  const float* x1    = (const float*)d_in[1];
  const float* x2    = (const float*)d_in[2];
  const float* x3    = (const float*)d_in[3];
  const float* W_ref = (const float*)d_in[4];
  const float* b_ref = (const float*)d_in[5];
  const float* W_off = (const float*)d_in[6];
  const float* b_off = (const float*)d_in[7];
  const float* W_aw  = (const float*)d_in[8];
  const float* b_aw  = (const float*)d_in[9];
  const float* W_val = (const float*)d_in[10];
  const float* b_val = (const float*)d_in[11];
  const float* W_outp= (const float*)d_in[12];
  const float* b_outp= (const float*)d_in[13];
  const float* gn_g  = (const float*)d_in[14];
  const float* gn_b  = (const float*)d_in[15];
  const float* Wc1   = (const float*)d_in[16];
  const float* bc1   = (const float*)d_in[17];
  const float* Wc2   = (const float*)d_in[18];
  const float* bc2   = (const float*)d_in[19];
  const float* Wc3   = (const float*)d_in[20];
  const float* bc3   = (const float*)d_in[21];
  const float* Wc4   = (const float*)d_in[22];
  const float* bc4   = (const float*)d_in[23];
  const float* Wc11  = (const float*)d_in[24];
  const float* bc11  = (const float*)d_in[25];
  const float* Wc22  = (const float*)d_in[26];
  const float* bc22  = (const float*)d_in[27];
  const float* Wc33  = (const float*)d_in[28];
  const float* bc33  = (const float*)d_in[29];
  const float* ln1_g = (const float*)d_in[30];
  const float* ln1_b = (const float*)d_in[31];
  const float* W1    = (const float*)d_in[32];
  const float* b1f   = (const float*)d_in[33];
  const float* W2    = (const float*)d_in[34];
  const float* b2f_  = (const float*)d_in[35];
  const float* ln2_g = (const float*)d_in[36];
  const float* ln2_b = (const float*)d_in[37];

  // ---- workspace (byte offsets) ----
  char* wsb = (char*)d_ws;
  float* src             = (float*)(wsb + 0);              // 27.3 MB; later h2 f32
  __hip_bfloat16* valb   = (__hip_bfloat16*)(wsb + WS_VALB); // bf16 value, 13.7 MB
  __hip_bfloat16* warena = (__hip_bfloat16*)(wsb + WS_VALB + 13663232); // 3.3 MB
  float* h1              = (float*)(wsb + 54652928);
  __hip_bfloat16* srcb   = (__hip_bfloat16*)(wsb + 81979392);
  __hip_bfloat16* h1b    = (__hip_bfloat16*)(wsb + 95642624);
  __hip_bfloat16* sampb  = (__hip_bfloat16*)(wsb + 109305856); // also h2b
  __hip_bfloat16* h2b    = sampb;
  __hip_bfloat16* midb   = (__hip_bfloat16*)(wsb + WS_R);      // 54.7 MB region R
  float* offb            = (float*)(wsb + WS_R);               // overlay R (pre-FFN)
  float* awb             = offb + (size_t)NLQ * 320;
  float* refb            = awb + (size_t)NLQ * 160;
  __hip_bfloat16* xt0    = (__hip_bfloat16*)(wsb + WS_R);      // overlay R (phase 1)
  __hip_bfloat16* xt2    = (__hip_bfloat16*)(wsb + WS_R + 5120000);
  __hip_bfloat16* xt3    = (__hip_bfloat16*)(wsb + WS_R + 6400000);
  float* stats           = (float*)(wsb + 177622016);          // 512 f32 raw sums
  float* catbias         = (float*)(wsb + 177624064);          // 746 f32
  const size_t needed = 177628160;
  if (ws_size < needed) return;

  // bf16 weight arena offsets (elements); first four form wWproj [746][256]
  __hip_bfloat16* wWproj = warena + 0;
  __hip_bfloat16* wW_val = warena + 0;
  __hip_bfloat16* wW_off = warena + 65536;
  __hip_bfloat16* wW_aw  = warena + 147456;
  __hip_bfloat16* wW_ref = warena + 188416;
  __hip_bfloat16* wW_out = warena + 190976;
  __hip_bfloat16* wW1    = warena + 256512;
  __hip_bfloat16* wW2    = warena + 518656;
  __hip_bfloat16* wWc1   = warena + 780800;
  __hip_bfloat16* wWc2   = warena + 813568;
  __hip_bfloat16* wWc3   = warena + 944640;
  __hip_bfloat16* wWc11  = warena + 1206784;
  __hip_bfloat16* wWc22  = warena + 1239552;
  __hip_bfloat16* wWc33  = warena + 1370624;

  dim3 B(256);

  // ---- weight conversion + bias concat + stats zero ----
  CvtTab tab = {{
    {W_val, wW_val, 65536}, {W_off, wW_off, 81920}, {W_aw, wW_aw, 40960},
    {W_ref, wW_ref, 2560},  {W_outp, wW_out, 65536},{W1, wW1, 262144},
    {W2, wW2, 262144},      {Wc1, wWc1, 32768},     {Wc2, wWc2, 131072},
    {Wc3, wWc3, 262144},    {Wc11, wWc11, 32768},   {Wc22, wWc22, 131072},
    {Wc33, wWc33, 262144}
  }};
  cvt_weights_k<<<dim3(1024,13),B,0,stream>>>(tab);
  cat_bias_k<<<3,B,0,stream>>>(b_val, b_off, b_aw, b_ref, catbias);
  hipMemsetAsync(stats, 0, 2048, stream);

  // ---- phase 1: transposes, convs, GN into src/srcb ----
  transpose_cl_k<<<dim3(313,4,2), B,0,stream>>>(x0, xt0, 128, 10000);
  transpose_cl_k<<<dim3(20,16,2), B,0,stream>>>(x2, xt2, 512, 625);
  transpose_cl_k<<<dim3(6,32,2),  B,0,stream>>>(x3, xt3, 1024, 169);
  mgemm_k<0,0,0><<<dim3(157,2),B,0,stream>>>(xt0, wWc1, bc1, src, 20000,256,128,128, 20000,0,0, 10000,LTOT,0);
  mgemm_k<0,0,0><<<dim3(10,2), B,0,stream>>>(xt2, wWc2, bc2, src, 1250,256,512,512, 1250,0,0, 625,LTOT,12500);
  mgemm_k<0,0,0><<<dim3(3,2),  B,0,stream>>>(xt3, wWc3, bc3, src, 338,256,1024,1024, 338,0,0, 169,LTOT,13125);
  biasinit_k<<<98,B,0,stream>>>(src, bc4);
  mgemm_k<1,3,1><<<dim3(1,2,32),B,0,stream>>>(xt3, Wc4, bc4, src, 98,256,9216,288, 0,0,0, 49,LTOT,13294);
  copy_lvl1_in_k<<<dim3(79,8,2),B,0,stream>>>(x1, src, srcb);
  gn_stats_k<<<dim3(171,2),B,0,stream>>>(src, stats);
  gn_apply_k<<<21686,B,0,stream>>>(src, srcb, stats, gn_g, gn_b);

  // ---- fused projections (val|off|aw|ref) + softmax + sampling ----
  mgemm_k<0,7,0><<<dim3(209,6),B,0,stream>>>(srcb, wWproj, catbias, d_ws, NLQ,746,256,256, NLQ,0,0, NLQ,0,0);
  softmax20_k<<<834,B,0,stream>>>(awb, NLQ * 8);
  msdeform_k<<<NLQ,B,0,stream>>>(valb, offb, awb, refb, sampb);

  // ---- out-proj + LN1 ----
  mgemm_k<0,0,0><<<dim3(209,2),B,0,stream>>>(sampb, wW_out, b_outp, h1, NLQ,256,256,256, NLQ,0,0, NLQ,0,0);
  ln_resid_k<<<NLQ,B,0,stream>>>(src, h1, h1b, ln1_g, ln1_b);

  // ---- FFN + LN2 (h2 f32 reuses src, dead after LN1) ----
  mgemm_k<0,2,0><<<dim3(209,8),B,0,stream>>>(h1b,  wW1, b1f,  midb, NLQ,1024,256,256, NLQ,0,0, NLQ,0,0);
  mgemm_k<0,0,0><<<dim3(209,2),B,0,stream>>>(midb, wW2, b2f_, src,  NLQ,256,1024,1024, NLQ,0,0, NLQ,0,0);
  ln_resid_k<<<NLQ,B,0,stream>>>(h1, src, h2b, ln2_g, ln2_b);

  // ---- output convs / copies ----
  float* out = (float*)d_out;
  mgemm_k<0,4,0><<<dim3(157,1),B,0,stream>>>(h2b, wWc11, bc11, out,           20000,128,256,256, 10000,LTOT,0,   10000,0,0);
  copy_lvl1_out_k<<<dim3(79,8,2),B,0,stream>>>(src, out + 2560000);
  mgemm_k<0,4,0><<<dim3(10,4), B,0,stream>>>(h2b, wWc22, bc22, out + 3840000, 1250,512,256,256,  625,LTOT,12500, 625,0,0);
  mgemm_k<0,4,0><<<dim3(3,8),  B,0,stream>>>(h2b, wWc33, bc33, out + 4480000, 338,1024,256,256,  169,LTOT,13125, 169,0,0);
}